// Round 10
// baseline (666.864 us; speedup 1.0000x reference)
//
#include <hip/hip_runtime.h>
#include <math.h>

#define NN 50000
#define NE 800000
#define DIN 32
#define D 128
#define NL 3
#define NG 64
#define LN_EPS 1e-5f
#define SCAN_BLOCKS 196   // ceil(NN/256)

typedef unsigned short u16;
typedef __bf16 bf16x8 __attribute__((ext_vector_type(8)));
typedef float f32x4 __attribute__((ext_vector_type(4)));

__device__ __forceinline__ float gelu_f(float x) {
    return 0.5f * x * (1.0f + erff(x * 0.70710678118654752f));
}

// tanh-approx gelu in sigmoid form: x*sigmoid(1.59576912*(x + 0.044715 x^3))
// max |err| vs exact ~1e-3; ~8 VALU ops (v_exp is 1 HW inst)
__device__ __forceinline__ float gelu_fast(float x) {
    float u = x * x;
    float y = x * fmaf(0.07135481627f, u, 1.5957691216f);
    float s = 1.0f / (1.0f + __expf(-y));
    return x * s;
}

__device__ __forceinline__ u16 f2bf(float x) {
    unsigned int u = __float_as_uint(x);
    u += 0x7fffu + ((u >> 16) & 1u);
    return (u16)(u >> 16);
}

// ---------------- CSR build: hist + 2-level scan + scatter ----------------
__global__ __launch_bounds__(256) void hist_kernel(
    const int* __restrict__ dst, int* __restrict__ hist)
{
    int e = blockIdx.x * 256 + threadIdx.x;
    atomicAdd(&hist[dst[e]], 1);
}

__global__ __launch_bounds__(256) void bsum_kernel(
    const int* __restrict__ hist, int* __restrict__ bsum)
{
    __shared__ int red[256];
    int i = blockIdx.x * 256 + threadIdx.x;
    red[threadIdx.x] = (i < NN) ? hist[i] : 0;
    __syncthreads();
    for (int off = 128; off > 0; off >>= 1) {
        if (threadIdx.x < off) red[threadIdx.x] += red[threadIdx.x + off];
        __syncthreads();
    }
    if (threadIdx.x == 0) bsum[blockIdx.x] = red[0];
}

__global__ __launch_bounds__(256) void bscan_kernel(
    const int* __restrict__ bsum, int* __restrict__ boff)
{
    __shared__ int sc[256];
    const int t = threadIdx.x;
    int orig = (t < SCAN_BLOCKS) ? bsum[t] : 0;
    sc[t] = orig;
    __syncthreads();
    for (int off = 1; off < 256; off <<= 1) {
        int v = (t >= off) ? sc[t - off] : 0;
        __syncthreads();
        sc[t] += v;
        __syncthreads();
    }
    if (t < SCAN_BLOCKS) boff[t] = sc[t] - orig;   // exclusive
}

__global__ __launch_bounds__(256) void emit_kernel(
    const int* __restrict__ hist, const int* __restrict__ boff,
    int* __restrict__ row_ptr, int* __restrict__ cursor)
{
    __shared__ int sc[256];
    const int t = threadIdx.x;
    const int i = blockIdx.x * 256 + t;
    int orig = (i < NN) ? hist[i] : 0;
    sc[t] = orig;
    __syncthreads();
    for (int off = 1; off < 256; off <<= 1) {
        int v = (t >= off) ? sc[t - off] : 0;
        __syncthreads();
        sc[t] += v;
        __syncthreads();
    }
    if (i < NN) {
        int ex = sc[t] - orig + boff[blockIdx.x];
        row_ptr[i] = ex;
        cursor[i] = ex;
    }
    if (i == 0) row_ptr[NN] = NE;
}

__global__ __launch_bounds__(256) void scatter_kernel(
    const int* __restrict__ src, const int* __restrict__ dst,
    const float* __restrict__ ew, int* __restrict__ cursor,
    int* __restrict__ sSrc, float* __restrict__ sEw)
{
    int e = blockIdx.x * 256 + threadIdx.x;
    int d = dst[e];
    int pos = atomicAdd(&cursor[d], 1);
    sSrc[pos] = src[e];
    sEw[pos] = ew[e];
}

// ---------------- projections / weight prep ----------------
__global__ __launch_bounds__(256) void input_proj_kernel(
    const float* __restrict__ X, const float* __restrict__ W,
    const float* __restrict__ b, u16* __restrict__ hbf)
{
    __shared__ float sW[DIN * D];
    for (int i = threadIdx.x; i < DIN * D; i += 256) sW[i] = W[i];
    __syncthreads();
    int o = blockIdx.x * 256 + threadIdx.x;
    int n = o >> 7, d = o & 127;
    const float* x = X + n * DIN;
    float acc = b[d];
#pragma unroll
    for (int k = 0; k < DIN; ++k) acc = fmaf(x[k], sW[k * D + d], acc);
    hbf[o] = f2bf(gelu_f(acc));
}

// merged 4-region transpose: dst[n*dstRS + k] = bf16(src[k*128 + n]) per region
__global__ __launch_bounds__(256) void transpose_all_kernel(
    const float* __restrict__ eW1, const float* __restrict__ uW1,
    const float* __restrict__ uW2,
    u16* __restrict__ PWT, u16* __restrict__ NW1T, u16* __restrict__ uW2T)
{
    const int region = blockIdx.x / 192;
    int i = (blockIdx.x - region * 192) * 256 + threadIdx.x;   // 0..49151 (NL*16384)
    int l = i / 16384;
    int r = i - l * 16384;
    int n = r >> 7, k = r & 127;        // n = out row, k = inner
    const float* srcp; u16* dstp; int srcLS, dstLS, dstRS, srcOff = 0, dstOff = 0;
    if (region == 0)      { srcp = eW1; dstp = PWT;  srcLS = 257 * 128; dstLS = 256 * 128; dstRS = 128; }
    else if (region == 1) { srcp = eW1; dstp = PWT;  srcLS = 257 * 128; dstLS = 256 * 128; dstRS = 128; srcOff = 128 * 128; dstOff = 128 * 128; }
    else if (region == 2) { srcp = uW1; dstp = NW1T; srcLS = 256 * 128; dstLS = 128 * 256; dstRS = 256; }
    else                  { srcp = uW2; dstp = uW2T; srcLS = 128 * 128; dstLS = 128 * 128; dstRS = 128; }
    dstp[(size_t)l * dstLS + dstOff + (size_t)n * dstRS + k] =
        f2bf(srcp[(size_t)l * srcLS + srcOff + (size_t)k * 128 + n]);
}

// NW1T[l][n][128+k] = bf16( sum_j eW2[l][k][j] * uW1[l][128+j][n] )
__global__ __launch_bounds__(256) void w2p_kernel(
    const float* __restrict__ eW2, const float* __restrict__ uW1,
    u16* __restrict__ NW1T)
{
    int i = blockIdx.x * 256 + threadIdx.x;       // NL*128*128
    int l = i / 16384;
    int r = i - l * 16384;
    int n = r >> 7, k = r & 127;
    const float* w2row = eW2 + (size_t)l * 16384 + k * 128;
    const float* u1col = uW1 + (size_t)l * 32768 + 128 * 128 + n;
    float s = 0.f;
#pragma unroll 4
    for (int j = 0; j < 128; ++j) s = fmaf(w2row[j], u1col[j * 128], s);
    NW1T[(size_t)l * 32768 + n * 256 + 128 + k] = f2bf(s);
}

// nb2p[l][n] = sum_j eb2[l][j] * uW1[l][128+j][n]
__global__ __launch_bounds__(128) void b2p_kernel(
    const float* __restrict__ eb2, const float* __restrict__ uW1,
    float* __restrict__ nb2p)
{
    int l = blockIdx.x, n = threadIdx.x;
    const float* b2r = eb2 + l * 128;
    const float* u1col = uW1 + (size_t)l * 32768 + 128 * 128 + n;
    float s = 0.f;
#pragma unroll 4
    for (int j = 0; j < 128; ++j) s = fmaf(b2r[j], u1col[j * 128], s);
    nb2p[l * 128 + n] = s;
}

// P[n][0:256] = hbf[n] @ [W1a | W1b]  (layer-0 only) — LDS-coalesced stores
__global__ __launch_bounds__(256) void proj_kernel(
    const u16* __restrict__ hbf, const u16* __restrict__ PWT,
    u16* __restrict__ P)
{
    __shared__ u16 sA[64 * 136];
    __shared__ u16 sP[64 * 264];
    const int tid = threadIdx.x;
    const int n0 = blockIdx.x * 64;
    {
        const int e = tid >> 2, q = tid & 3;
        int n = n0 + e; if (n >= NN) n = NN - 1;
        const uint4* hs = (const uint4*)(hbf + (size_t)n * D);
        uint4* ar = (uint4*)(sA + e * 136);
#pragma unroll
        for (int c = 0; c < 4; ++c) ar[q * 4 + c] = hs[q * 4 + c];
    }
    __syncthreads();

    const int lane = tid & 63;
    const int l15 = lane & 15;
    const int quad = lane >> 4;
    const int nbase = (tid >> 6) * 64;

    f32x4 acc[4][4];
#pragma unroll
    for (int mt = 0; mt < 4; ++mt)
#pragma unroll
        for (int nt = 0; nt < 4; ++nt) acc[mt][nt] = (f32x4){0.f, 0.f, 0.f, 0.f};

#pragma unroll
    for (int kb = 0; kb < 128; kb += 32) {
        bf16x8 bf[4];
#pragma unroll
        for (int nt = 0; nt < 4; ++nt)
            bf[nt] = *(const bf16x8*)(PWT + (size_t)(nbase + nt * 16 + l15) * 128 + quad * 8 + kb);
#pragma unroll
        for (int mt = 0; mt < 4; ++mt) {
            bf16x8 af = *(const bf16x8*)(sA + (mt * 16 + l15) * 136 + quad * 8 + kb);
#pragma unroll
            for (int nt = 0; nt < 4; ++nt)
                acc[mt][nt] = __builtin_amdgcn_mfma_f32_16x16x32_bf16(af, bf[nt], acc[mt][nt], 0, 0, 0);
        }
    }

#pragma unroll
    for (int mt = 0; mt < 4; ++mt)
#pragma unroll
        for (int nt = 0; nt < 4; ++nt) {
            const int col = nbase + nt * 16 + l15;
#pragma unroll
            for (int r = 0; r < 4; ++r)
                sP[(mt * 16 + quad * 4 + r) * 264 + col] = f2bf(acc[mt][nt][r]);
        }
    __syncthreads();
    {
        const int e = tid >> 2, q = tid & 3;
        const int n = n0 + e;
        if (n < NN) {
            uint4* op = (uint4*)(P + (size_t)n * 256);
            const u16* sp = sP + e * 264;
#pragma unroll
            for (int c = 0; c < 8; ++c) op[q + c * 4] = *(const uint4*)(sp + (q + c * 4) * 8);
        }
    }
}

// CSR edge pass: one wave per dst node, lane owns 2 cols. Zero atomics.
__global__ __launch_bounds__(256) void edge_csr_kernel(
    const u16* __restrict__ P, const int* __restrict__ sSrc,
    const float* __restrict__ sEw, const int* __restrict__ row_ptr,
    const float* __restrict__ W1last, const float* __restrict__ b1,
    u16* __restrict__ Sbf)
{
    const int n = (blockIdx.x * 256 + threadIdx.x) >> 6;
    if (n >= NN) return;
    const int lane = threadIdx.x & 63;
    const int c2 = lane * 2;

    const float wl0 = W1last[c2], wl1 = W1last[c2 + 1];
    unsigned p2 = *(const unsigned*)(P + (size_t)n * 256 + 128 + c2);
    const float t20 = __uint_as_float(p2 << 16) + b1[c2];
    const float t21 = __uint_as_float(p2 & 0xffff0000u) + b1[c2 + 1];

    float a0 = 0.f, a1 = 0.f;
    const int beg = row_ptr[n], end = row_ptr[n + 1];
    int e = beg;
    for (; e + 1 < end; e += 2) {
        const int s0 = sSrc[e], s1 = sSrc[e + 1];
        const float w0 = sEw[e], w1 = sEw[e + 1];
        unsigned pa = *(const unsigned*)(P + (size_t)s0 * 256 + c2);
        unsigned pb = *(const unsigned*)(P + (size_t)s1 * 256 + c2);
        a0 += gelu_fast(__uint_as_float(pa << 16) + t20 + w0 * wl0);
        a1 += gelu_fast(__uint_as_float(pa & 0xffff0000u) + t21 + w0 * wl1);
        a0 += gelu_fast(__uint_as_float(pb << 16) + t20 + w1 * wl0);
        a1 += gelu_fast(__uint_as_float(pb & 0xffff0000u) + t21 + w1 * wl1);
    }
    if (e < end) {
        const int s0 = sSrc[e];
        const float w0 = sEw[e];
        unsigned pa = *(const unsigned*)(P + (size_t)s0 * 256 + c2);
        a0 += gelu_fast(__uint_as_float(pa << 16) + t20 + w0 * wl0);
        a1 += gelu_fast(__uint_as_float(pa & 0xffff0000u) + t21 + w0 * wl1);
    }
    unsigned pk = (unsigned)f2bf(a0) | ((unsigned)f2bf(a1) << 16);
    *(unsigned*)(Sbf + (size_t)n * D + c2) = pk;
}

// Node update on MFMA + residual + LayerNorm; optional fused next-layer P-GEMM;
// fused pooling accumulation on the last layer (write_f32).
__global__ __launch_bounds__(256, 3) void node_mfma_kernel(
    const u16* __restrict__ hbf, const u16* __restrict__ Sbf,
    const int* __restrict__ hist,
    const u16* __restrict__ NW1T, const float* __restrict__ ub1,
    const float* __restrict__ nb2p,
    const u16* __restrict__ W2T, const float* __restrict__ b2,
    const float* __restrict__ gamma, const float* __restrict__ beta,
    float* __restrict__ hidden_out, u16* __restrict__ hbf_out,
    const u16* __restrict__ PWTnext, u16* __restrict__ Pout, int write_f32,
    const int* __restrict__ batch, float* __restrict__ pooled)
{
    __shared__ u16 sA[64 * 264];
    __shared__ u16 sH1[64 * 136];
    __shared__ float s_cnt[64];
    __shared__ int s_b[64];
    float* sR = (float*)sA;
    const int tid = threadIdx.x;
    const int n0 = blockIdx.x * 64;

    if (tid < 64) {
        int n = n0 + tid;
        s_b[tid] = (write_f32 && n < NN) ? batch[n] : -1;
        if (n >= NN) n = NN - 1;
        s_cnt[tid] = (float)hist[n];
    }
    {   // stage A = [hbf | Sbf] (both bf16): 32 uint4 chunks/row, 8 per thread
        const int e = tid >> 2, q = tid & 3;
        int n = n0 + e; if (n >= NN) n = NN - 1;
        const uint4* hs = (const uint4*)(hbf + (size_t)n * D);
        const uint4* ss = (const uint4*)(Sbf + (size_t)n * D);
        uint4* ar = (uint4*)(sA + e * 264);
#pragma unroll
        for (int c = 0; c < 8; ++c) {
            int cc = q * 8 + c;
            ar[cc] = (cc < 16) ? hs[cc] : ss[cc - 16];
        }
    }
    __syncthreads();

    const int lane = tid & 63;
    const int l15 = lane & 15;
    const int quad = lane >> 4;
    const int nbase = (tid >> 6) * 32;

    f32x4 acc[4][2];
#pragma unroll
    for (int mt = 0; mt < 4; ++mt)
#pragma unroll
        for (int nt = 0; nt < 2; ++nt) acc[mt][nt] = (f32x4){0.f, 0.f, 0.f, 0.f};

    const u16* bp0 = NW1T + (size_t)(nbase + l15) * 256 + quad * 8;
    const u16* bp1 = bp0 + 16 * 256;
#pragma unroll
    for (int kb = 0; kb < 256; kb += 32) {
        bf16x8 bf0 = *(const bf16x8*)(bp0 + kb);
        bf16x8 bf1 = *(const bf16x8*)(bp1 + kb);
#pragma unroll
        for (int mt = 0; mt < 4; ++mt) {
            bf16x8 af = *(const bf16x8*)(sA + (mt * 16 + l15) * 264 + quad * 8 + kb);
            acc[mt][0] = __builtin_amdgcn_mfma_f32_16x16x32_bf16(af, bf0, acc[mt][0], 0, 0, 0);
            acc[mt][1] = __builtin_amdgcn_mfma_f32_16x16x32_bf16(af, bf1, acc[mt][1], 0, 0, 0);
        }
    }

    // epilogue 1: + ub1 + cnt*b2'; gelu -> sH1
#pragma unroll
    for (int mt = 0; mt < 4; ++mt)
#pragma unroll
        for (int nt = 0; nt < 2; ++nt) {
            const int col = nbase + nt * 16 + l15;
            const float bb = ub1[col];
            const float bp = nb2p[col];
#pragma unroll
            for (int r = 0; r < 4; ++r) {
                const int row = mt * 16 + quad * 4 + r;
                float v = acc[mt][nt][r] + bb + s_cnt[row] * bp;
                sH1[row * 136 + col] = f2bf(gelu_f(v));
            }
        }
    __syncthreads();

    f32x4 acc2[4][2];
#pragma unroll
    for (int mt = 0; mt < 4; ++mt)
#pragma unroll
        for (int nt = 0; nt < 2; ++nt) acc2[mt][nt] = (f32x4){0.f, 0.f, 0.f, 0.f};

    const u16* cp0 = W2T + (size_t)(nbase + l15) * 128 + quad * 8;
    const u16* cp1 = cp0 + 16 * 128;
#pragma unroll
    for (int kb = 0; kb < 128; kb += 32) {
        bf16x8 bf0 = *(const bf16x8*)(cp0 + kb);
        bf16x8 bf1 = *(const bf16x8*)(cp1 + kb);
#pragma unroll
        for (int mt = 0; mt < 4; ++mt) {
            bf16x8 af = *(const bf16x8*)(sH1 + (mt * 16 + l15) * 136 + quad * 8 + kb);
            acc2[mt][0] = __builtin_amdgcn_mfma_f32_16x16x32_bf16(af, bf0, acc2[mt][0], 0, 0, 0);
            acc2[mt][1] = __builtin_amdgcn_mfma_f32_16x16x32_bf16(af, bf1, acc2[mt][1], 0, 0, 0);
        }
    }

    // r = hbf + u -> sR (fp32)
#pragma unroll
    for (int mt = 0; mt < 4; ++mt)
#pragma unroll
        for (int nt = 0; nt < 2; ++nt) {
            const int col = nbase + nt * 16 + l15;
            const float bb = b2[col];
#pragma unroll
            for (int r = 0; r < 4; ++r) {
                const int row = mt * 16 + quad * 4 + r;
                int n = n0 + row; if (n >= NN) n = NN - 1;
                float h = __uint_as_float((unsigned)hbf[(size_t)n * D + col] << 16);
                sR[row * 132 + col] = acc2[mt][nt][r] + bb + h;
            }
        }
    __syncthreads();   // GEMM2's sH1 reads done; sR ready

    // LayerNorm: 4 threads/node, 32 cols each; bf16 -> sH1, f32 -> sR (if needed)
    {
        const int e = tid >> 2, t4 = tid & 3;
        float* rr = sR + e * 132 + t4 * 32;
        float s1 = 0.f, s2 = 0.f;
        float4 v[8];
#pragma unroll
        for (int i = 0; i < 8; ++i) {
            v[i] = *(const float4*)(rr + i * 4);
            s1 += v[i].x + v[i].y + v[i].z + v[i].w;
            s2 += v[i].x * v[i].x + v[i].y * v[i].y + v[i].z * v[i].z + v[i].w * v[i].w;
        }
        s1 += __shfl_xor(s1, 1); s2 += __shfl_xor(s2, 1);
        s1 += __shfl_xor(s1, 2); s2 += __shfl_xor(s2, 2);
        const float mean = s1 * (1.f / 128.f);
        const float var = s2 * (1.f / 128.f) - mean * mean;
        const float rs = rsqrtf(var + LN_EPS);
#pragma unroll
        for (int i = 0; i < 8; ++i) {
            const float4 g = *(const float4*)(gamma + t4 * 32 + i * 4);
            const float4 be = *(const float4*)(beta + t4 * 32 + i * 4);
            float4 o;
            o.x = (v[i].x - mean) * rs * g.x + be.x;
            o.y = (v[i].y - mean) * rs * g.y + be.y;
            o.z = (v[i].z - mean) * rs * g.z + be.z;
            o.w = (v[i].w - mean) * rs * g.w + be.w;
            uint2 pk;
            pk.x = (unsigned)f2bf(o.x) | ((unsigned)f2bf(o.y) << 16);
            pk.y = (unsigned)f2bf(o.z) | ((unsigned)f2bf(o.w) << 16);
            *(uint2*)(sH1 + e * 136 + t4 * 32 + i * 4) = pk;
            if (write_f32) *(float4*)(rr + i * 4) = o;   // stage normalized f32
        }
    }
    __syncthreads();

    // cooperative coalesced stores
    {
        const int e = tid >> 2, q = tid & 3;
        const int n = n0 + e;
        if (n < NN) {
            uint4* hp = (uint4*)(hbf_out + (size_t)n * D);       // 16 chunks/row
            const u16* sh = sH1 + e * 136;
#pragma unroll
            for (int c = 0; c < 4; ++c) hp[q + c * 4] = *(const uint4*)(sh + (q + c * 4) * 8);
            if (write_f32) {
                float4* op = (float4*)(hidden_out + (size_t)n * D);  // 32 chunks/row
                const float* sr = sR + e * 132;
#pragma unroll
                for (int c = 0; c < 8; ++c) op[q + c * 4] = *(const float4*)(sr + (q + c * 4) * 4);
            }
        }
    }

    // fused pooling accumulation (last layer): run-length over sorted batch
    if (write_f32) {
        const int col = tid & 127, half = tid >> 7;
        const int base = half * 32;
        int cur = s_b[base];
        float acc_p = 0.f;
        for (int i = 0; i < 32; ++i) {
            int b = s_b[base + i];
            if (b < 0) break;
            if (b != cur) { atomicAdd(&pooled[cur * D + col], acc_p); cur = b; acc_p = 0.f; }
            acc_p += sR[(base + i) * 132 + col];
        }
        if (cur >= 0) atomicAdd(&pooled[cur * D + col], acc_p);
    }

    // fused next-layer projection: P = h_new @ PWTnext  (M=64, K=128, N=256)
    if (PWTnext) {
        const int nbase4 = (tid >> 6) * 64;
        f32x4 accp[4][4];
#pragma unroll
        for (int mt = 0; mt < 4; ++mt)
#pragma unroll
            for (int nt = 0; nt < 4; ++nt) accp[mt][nt] = (f32x4){0.f, 0.f, 0.f, 0.f};

#pragma unroll
        for (int kb = 0; kb < 128; kb += 32) {
            bf16x8 bf[4];
#pragma unroll
            for (int nt = 0; nt < 4; ++nt)
                bf[nt] = *(const bf16x8*)(PWTnext + (size_t)(nbase4 + nt * 16 + l15) * 128 + quad * 8 + kb);
#pragma unroll
            for (int mt = 0; mt < 4; ++mt) {
                bf16x8 af = *(const bf16x8*)(sH1 + (mt * 16 + l15) * 136 + quad * 8 + kb);
#pragma unroll
                for (int nt = 0; nt < 4; ++nt)
                    accp[mt][nt] = __builtin_amdgcn_mfma_f32_16x16x32_bf16(af, bf[nt], accp[mt][nt], 0, 0, 0);
            }
        }
        __syncthreads();   // sR/sA reads done before sP overwrite
        u16* sP = sA;      // reuse as u16 64x264
#pragma unroll
        for (int mt = 0; mt < 4; ++mt)
#pragma unroll
            for (int nt = 0; nt < 4; ++nt) {
                const int col = nbase4 + nt * 16 + l15;
#pragma unroll
                for (int r = 0; r < 4; ++r)
                    sP[(mt * 16 + quad * 4 + r) * 264 + col] = f2bf(accp[mt][nt][r]);
            }
        __syncthreads();
        const int e = tid >> 2, q = tid & 3;
        const int n = n0 + e;
        if (n < NN) {
            uint4* op = (uint4*)(Pout + (size_t)n * 256);        // 32 chunks/row
            const u16* sp = sP + e * 264;
#pragma unroll
            for (int c = 0; c < 8; ++c) op[q + c * 4] = *(const uint4*)(sp + (q + c * 4) * 8);
        }
    }
}

// ---------------- pooling tail ----------------
__global__ __launch_bounds__(256) void count_kernel(
    const int* __restrict__ batch, float* __restrict__ counts)
{
    int t = blockIdx.x * 256 + threadIdx.x;
    const int chunk = (NN + 8191) / 8192;
    int beg = t * chunk, end = beg + chunk;
    if (end > NN) end = NN;
    if (beg >= NN) return;
    int cur = batch[beg];
    float cnt = 0.f;
    for (int i = beg; i < end; ++i) {
        int b = batch[i];
        if (b != cur) { atomicAdd(&counts[cur], cnt); cur = b; cnt = 0.f; }
        cnt += 1.f;
    }
    atomicAdd(&counts[cur], cnt);
}

__global__ __launch_bounds__(256) void pool_div_kernel(
    float* __restrict__ pooled, const float* __restrict__ counts)
{
    int i = blockIdx.x * 256 + threadIdx.x;
    pooled[i] /= fmaxf(counts[i >> 7], 1.0f);
}

extern "C" void kernel_launch(void* const* d_in, const int* in_sizes, int n_in,
                              void* d_out, int out_size, void* d_ws, size_t ws_size,
                              hipStream_t stream) {
    const float* X     = (const float*)d_in[0];
    const int*   eidx  = (const int*)d_in[1];
    const float* ew    = (const float*)d_in[2];
    const int*   batch = (const int*)d_in[3];
    const float* W_in  = (const float*)d_in[5];
    const float* b_in  = (const float*)d_in[6];
    const float* eW1   = (const float*)d_in[7];
    const float* eb1   = (const float*)d_in[8];
    const float* eW2   = (const float*)d_in[9];
    const float* eb2   = (const float*)d_in[10];
    const float* uW1   = (const float*)d_in[11];
    const float* ub1   = (const float*)d_in[12];
    const float* uW2   = (const float*)d_in[13];
    const float* ub2   = (const float*)d_in[14];
    const float* gamma = (const float*)d_in[15];
    const float* beta  = (const float*)d_in[16];

    float* out_hidden = (float*)d_out;
    float* out_pooled = out_hidden + (size_t)NN * D;

    u16*   hbf  = (u16*)d_ws;                                  // N*128 bf16
    u16*   P    = hbf + (size_t)NN * D;                        // N*256 bf16
    u16*   Sbf  = P + (size_t)NN * 256;                        // N*128 bf16
    u16*   PWT  = Sbf + (size_t)NN * D;                        // NL*256*128
    u16*   NW1T = PWT + (size_t)NL * 256 * 128;                // NL*128*256
    u16*   uW2T = NW1T + (size_t)NL * 128 * 256;               // NL*128*128
    float* nb2p = (float*)(uW2T + (size_t)NL * 128 * 128);     // NL*128
    int*   hist    = (int*)(nb2p + (size_t)NL * 128);
    int*   row_ptr = hist + NN;                                // NN+1 ints
    int*   cursor  = row_ptr + NN + 1;
    int*   bsum    = cursor + NN;                              // SCAN_BLOCKS
    int*   boff    = bsum + SCAN_BLOCKS;                       // SCAN_BLOCKS
    int*   sSrc    = boff + SCAN_BLOCKS;
    float* sEw     = (float*)(sSrc + NE);
    float* counts  = sEw + NE;

    const int* src = eidx;
    const int* dst = eidx + NE;

    // CSR build (parallel 2-level scan)
    hipMemsetAsync(hist, 0, (size_t)NN * sizeof(int), stream);
    hist_kernel<<<NE / 256, 256, 0, stream>>>(dst, hist);
    bsum_kernel<<<SCAN_BLOCKS, 256, 0, stream>>>(hist, bsum);
    bscan_kernel<<<1, 256, 0, stream>>>(bsum, boff);
    emit_kernel<<<SCAN_BLOCKS, 256, 0, stream>>>(hist, boff, row_ptr, cursor);
    scatter_kernel<<<NE / 256, 256, 0, stream>>>(src, dst, ew, cursor, sSrc, sEw);

    // weight prep
    transpose_all_kernel<<<4 * 192, 256, 0, stream>>>(eW1, uW1, uW2, PWT, NW1T, uW2T);
    w2p_kernel<<<192, 256, 0, stream>>>(eW2, uW1, NW1T);
    b2p_kernel<<<NL, 128, 0, stream>>>(eb2, uW1, nb2p);

    input_proj_kernel<<<(NN * D) / 256, 256, 0, stream>>>(X, W_in, b_in, hbf);

    // pooling buffers ready before the fused last-layer accumulation
    hipMemsetAsync(out_pooled, 0, (size_t)NG * D * sizeof(float), stream);
    hipMemsetAsync(counts, 0, (size_t)NG * sizeof(float), stream);
    count_kernel<<<32, 256, 0, stream>>>(batch, counts);

    const int nblk = (NN + 63) / 64;
    proj_kernel<<<nblk, 256, 0, stream>>>(hbf, PWT, P);   // layer-0 P
    for (int l = 0; l < NL; ++l) {
        edge_csr_kernel<<<(NN * 64 + 255) / 256, 256, 0, stream>>>(
            P, sSrc, sEw, row_ptr,
            eW1 + (size_t)l * 257 * 128 + 256 * 128,
            eb1 + (size_t)l * D, Sbf);
        const u16* pwt_next = (l < NL - 1) ? (PWT + (size_t)(l + 1) * 256 * 128) : nullptr;
        node_mfma_kernel<<<nblk, 256, 0, stream>>>(
            hbf, Sbf, hist,
            NW1T + (size_t)l * 128 * 256, ub1 + (size_t)l * D, nb2p + (size_t)l * D,
            uW2T + (size_t)l * 128 * 128, ub2 + (size_t)l * D,
            gamma + (size_t)l * D, beta + (size_t)l * D,
            out_hidden, hbf, pwt_next, P, (l == NL - 1) ? 1 : 0,
            batch, out_pooled);
    }

    pool_div_kernel<<<(NG * D) / 256, 256, 0, stream>>>(out_pooled, counts);
}

// Round 11
// 614.616 us; speedup vs baseline: 1.0850x; 1.0850x over previous
//
#include <hip/hip_runtime.h>
#include <math.h>

#define NN 50000
#define NE 800000
#define DIN 32
#define D 128
#define NL 3
#define NG 64
#define LN_EPS 1e-5f
#define SCAN_BLOCKS 196   // ceil(NN/256)

typedef unsigned short u16;
typedef __bf16 bf16x8 __attribute__((ext_vector_type(8)));
typedef float f32x4 __attribute__((ext_vector_type(4)));

__device__ __forceinline__ float gelu_f(float x) {
    return 0.5f * x * (1.0f + erff(x * 0.70710678118654752f));
}

// tanh-approx gelu, all-native: x * rcp(1 + exp2(-log2e*1.5957691*(x + 0.044715 x^3)))
// v_mul + v_fma + v_mul + v_exp + v_add + v_rcp + v_mul = 7 HW ops, no div sequence
__device__ __forceinline__ float gelu_fast(float x) {
    float u = x * x;
    float z = x * fmaf(-0.1029432f, u, -2.3022082f);   // = -log2e * 1.5957691*(x + 0.044715x^3) / x * x
    float e = __builtin_amdgcn_exp2f(z);
    float s = __builtin_amdgcn_rcpf(1.0f + e);
    return x * s;
}

__device__ __forceinline__ u16 f2bf(float x) {
    unsigned int u = __float_as_uint(x);
    u += 0x7fffu + ((u >> 16) & 1u);
    return (u16)(u >> 16);
}

// ---------------- CSR build: hist + 2-level scan + scatter ----------------
__global__ __launch_bounds__(256) void hist_kernel(
    const int* __restrict__ dst, int* __restrict__ hist)
{
    int e = blockIdx.x * 256 + threadIdx.x;
    atomicAdd(&hist[dst[e]], 1);
}

__global__ __launch_bounds__(256) void bsum_kernel(
    const int* __restrict__ hist, int* __restrict__ bsum)
{
    __shared__ int red[256];
    int i = blockIdx.x * 256 + threadIdx.x;
    red[threadIdx.x] = (i < NN) ? hist[i] : 0;
    __syncthreads();
    for (int off = 128; off > 0; off >>= 1) {
        if (threadIdx.x < off) red[threadIdx.x] += red[threadIdx.x + off];
        __syncthreads();
    }
    if (threadIdx.x == 0) bsum[blockIdx.x] = red[0];
}

__global__ __launch_bounds__(256) void bscan_kernel(
    const int* __restrict__ bsum, int* __restrict__ boff)
{
    __shared__ int sc[256];
    const int t = threadIdx.x;
    int orig = (t < SCAN_BLOCKS) ? bsum[t] : 0;
    sc[t] = orig;
    __syncthreads();
    for (int off = 1; off < 256; off <<= 1) {
        int v = (t >= off) ? sc[t - off] : 0;
        __syncthreads();
        sc[t] += v;
        __syncthreads();
    }
    if (t < SCAN_BLOCKS) boff[t] = sc[t] - orig;   // exclusive
}

__global__ __launch_bounds__(256) void emit_kernel(
    const int* __restrict__ hist, const int* __restrict__ boff,
    int* __restrict__ row_ptr, int* __restrict__ cursor)
{
    __shared__ int sc[256];
    const int t = threadIdx.x;
    const int i = blockIdx.x * 256 + t;
    int orig = (i < NN) ? hist[i] : 0;
    sc[t] = orig;
    __syncthreads();
    for (int off = 1; off < 256; off <<= 1) {
        int v = (t >= off) ? sc[t - off] : 0;
        __syncthreads();
        sc[t] += v;
        __syncthreads();
    }
    if (i < NN) {
        int ex = sc[t] - orig + boff[blockIdx.x];
        row_ptr[i] = ex;
        cursor[i] = ex;
    }
    if (i == 0) row_ptr[NN] = NE;
}

__global__ __launch_bounds__(256) void scatter_kernel(
    const int* __restrict__ src, const int* __restrict__ dst,
    const float* __restrict__ ew, int* __restrict__ cursor,
    int* __restrict__ sSrc, float* __restrict__ sEw)
{
    int e = blockIdx.x * 256 + threadIdx.x;
    int d = dst[e];
    int pos = atomicAdd(&cursor[d], 1);
    sSrc[pos] = src[e];
    sEw[pos] = ew[e];
}

// ---------------- projections / weight prep ----------------
__global__ __launch_bounds__(256) void input_proj_kernel(
    const float* __restrict__ X, const float* __restrict__ W,
    const float* __restrict__ b, u16* __restrict__ hbf)
{
    __shared__ float sW[DIN * D];
    for (int i = threadIdx.x; i < DIN * D; i += 256) sW[i] = W[i];
    __syncthreads();
    int o = blockIdx.x * 256 + threadIdx.x;
    int n = o >> 7, d = o & 127;
    const float* x = X + n * DIN;
    float acc = b[d];
#pragma unroll
    for (int k = 0; k < DIN; ++k) acc = fmaf(x[k], sW[k * D + d], acc);
    hbf[o] = f2bf(gelu_f(acc));
}

// merged 4-region transpose: dst[n*dstRS + k] = bf16(src[k*128 + n]) per region
__global__ __launch_bounds__(256) void transpose_all_kernel(
    const float* __restrict__ eW1, const float* __restrict__ uW1,
    const float* __restrict__ uW2,
    u16* __restrict__ PWT, u16* __restrict__ NW1T, u16* __restrict__ uW2T)
{
    const int region = blockIdx.x / 192;
    int i = (blockIdx.x - region * 192) * 256 + threadIdx.x;   // 0..49151 (NL*16384)
    int l = i / 16384;
    int r = i - l * 16384;
    int n = r >> 7, k = r & 127;
    const float* srcp; u16* dstp; int srcLS, dstLS, dstRS, srcOff = 0, dstOff = 0;
    if (region == 0)      { srcp = eW1; dstp = PWT;  srcLS = 257 * 128; dstLS = 256 * 128; dstRS = 128; }
    else if (region == 1) { srcp = eW1; dstp = PWT;  srcLS = 257 * 128; dstLS = 256 * 128; dstRS = 128; srcOff = 128 * 128; dstOff = 128 * 128; }
    else if (region == 2) { srcp = uW1; dstp = NW1T; srcLS = 256 * 128; dstLS = 128 * 256; dstRS = 256; }
    else                  { srcp = uW2; dstp = uW2T; srcLS = 128 * 128; dstLS = 128 * 128; dstRS = 128; }
    dstp[(size_t)l * dstLS + dstOff + (size_t)n * dstRS + k] =
        f2bf(srcp[(size_t)l * srcLS + srcOff + (size_t)k * 128 + n]);
}

// NW1T[l][n][128+k] = bf16( sum_j eW2[l][k][j] * uW1[l][128+j][n] )
__global__ __launch_bounds__(256) void w2p_kernel(
    const float* __restrict__ eW2, const float* __restrict__ uW1,
    u16* __restrict__ NW1T)
{
    int i = blockIdx.x * 256 + threadIdx.x;       // NL*128*128
    int l = i / 16384;
    int r = i - l * 16384;
    int n = r >> 7, k = r & 127;
    const float* w2row = eW2 + (size_t)l * 16384 + k * 128;
    const float* u1col = uW1 + (size_t)l * 32768 + 128 * 128 + n;
    float s = 0.f;
#pragma unroll 4
    for (int j = 0; j < 128; ++j) s = fmaf(w2row[j], u1col[j * 128], s);
    NW1T[(size_t)l * 32768 + n * 256 + 128 + k] = f2bf(s);
}

// nb2p[l][n] = sum_j eb2[l][j] * uW1[l][128+j][n]
__global__ __launch_bounds__(128) void b2p_kernel(
    const float* __restrict__ eb2, const float* __restrict__ uW1,
    float* __restrict__ nb2p)
{
    int l = blockIdx.x, n = threadIdx.x;
    const float* b2r = eb2 + l * 128;
    const float* u1col = uW1 + (size_t)l * 32768 + 128 * 128 + n;
    float s = 0.f;
#pragma unroll 4
    for (int j = 0; j < 128; ++j) s = fmaf(b2r[j], u1col[j * 128], s);
    nb2p[l * 128 + n] = s;
}

// P[n][0:256] = hbf[n] @ [W1a | W1b]  (layer-0 only) — LDS-coalesced stores
__global__ __launch_bounds__(256) void proj_kernel(
    const u16* __restrict__ hbf, const u16* __restrict__ PWT,
    u16* __restrict__ P)
{
    __shared__ u16 sA[64 * 136];
    __shared__ u16 sP[64 * 264];
    const int tid = threadIdx.x;
    const int n0 = blockIdx.x * 64;
    {
        const int e = tid >> 2, q = tid & 3;
        int n = n0 + e; if (n >= NN) n = NN - 1;
        const uint4* hs = (const uint4*)(hbf + (size_t)n * D);
        uint4* ar = (uint4*)(sA + e * 136);
#pragma unroll
        for (int c = 0; c < 4; ++c) ar[q * 4 + c] = hs[q * 4 + c];
    }
    __syncthreads();

    const int lane = tid & 63;
    const int l15 = lane & 15;
    const int quad = lane >> 4;
    const int nbase = (tid >> 6) * 64;

    f32x4 acc[4][4];
#pragma unroll
    for (int mt = 0; mt < 4; ++mt)
#pragma unroll
        for (int nt = 0; nt < 4; ++nt) acc[mt][nt] = (f32x4){0.f, 0.f, 0.f, 0.f};

#pragma unroll
    for (int kb = 0; kb < 128; kb += 32) {
        bf16x8 bf[4];
#pragma unroll
        for (int nt = 0; nt < 4; ++nt)
            bf[nt] = *(const bf16x8*)(PWT + (size_t)(nbase + nt * 16 + l15) * 128 + quad * 8 + kb);
#pragma unroll
        for (int mt = 0; mt < 4; ++mt) {
            bf16x8 af = *(const bf16x8*)(sA + (mt * 16 + l15) * 136 + quad * 8 + kb);
#pragma unroll
            for (int nt = 0; nt < 4; ++nt)
                acc[mt][nt] = __builtin_amdgcn_mfma_f32_16x16x32_bf16(af, bf[nt], acc[mt][nt], 0, 0, 0);
        }
    }

#pragma unroll
    for (int mt = 0; mt < 4; ++mt)
#pragma unroll
        for (int nt = 0; nt < 4; ++nt) {
            const int col = nbase + nt * 16 + l15;
#pragma unroll
            for (int r = 0; r < 4; ++r)
                sP[(mt * 16 + quad * 4 + r) * 264 + col] = f2bf(acc[mt][nt][r]);
        }
    __syncthreads();
    {
        const int e = tid >> 2, q = tid & 3;
        const int n = n0 + e;
        if (n < NN) {
            uint4* op = (uint4*)(P + (size_t)n * 256);
            const u16* sp = sP + e * 264;
#pragma unroll
            for (int c = 0; c < 8; ++c) op[q + c * 4] = *(const uint4*)(sp + (q + c * 4) * 8);
        }
    }
}

// CSR edge pass: one wave per dst node, lane owns 2 cols. Zero atomics.
__global__ __launch_bounds__(256) void edge_csr_kernel(
    const u16* __restrict__ P, const int* __restrict__ sSrc,
    const float* __restrict__ sEw, const int* __restrict__ row_ptr,
    const float* __restrict__ W1last, const float* __restrict__ b1,
    u16* __restrict__ Sbf)
{
    const int n = (blockIdx.x * 256 + threadIdx.x) >> 6;
    if (n >= NN) return;
    const int lane = threadIdx.x & 63;
    const int c2 = lane * 2;

    const float wl0 = W1last[c2], wl1 = W1last[c2 + 1];
    unsigned p2 = *(const unsigned*)(P + (size_t)n * 256 + 128 + c2);
    const float t20 = __uint_as_float(p2 << 16) + b1[c2];
    const float t21 = __uint_as_float(p2 & 0xffff0000u) + b1[c2 + 1];

    float a0 = 0.f, a1 = 0.f;
    const int beg = row_ptr[n], end = row_ptr[n + 1];
    int e = beg;
    for (; e + 1 < end; e += 2) {
        const int s0 = sSrc[e], s1 = sSrc[e + 1];
        const float w0 = sEw[e], w1 = sEw[e + 1];
        unsigned pa = *(const unsigned*)(P + (size_t)s0 * 256 + c2);
        unsigned pb = *(const unsigned*)(P + (size_t)s1 * 256 + c2);
        a0 += gelu_fast(__uint_as_float(pa << 16) + t20 + w0 * wl0);
        a1 += gelu_fast(__uint_as_float(pa & 0xffff0000u) + t21 + w0 * wl1);
        a0 += gelu_fast(__uint_as_float(pb << 16) + t20 + w1 * wl0);
        a1 += gelu_fast(__uint_as_float(pb & 0xffff0000u) + t21 + w1 * wl1);
    }
    if (e < end) {
        const int s0 = sSrc[e];
        const float w0 = sEw[e];
        unsigned pa = *(const unsigned*)(P + (size_t)s0 * 256 + c2);
        a0 += gelu_fast(__uint_as_float(pa << 16) + t20 + w0 * wl0);
        a1 += gelu_fast(__uint_as_float(pa & 0xffff0000u) + t21 + w0 * wl1);
    }
    unsigned pk = (unsigned)f2bf(a0) | ((unsigned)f2bf(a1) << 16);
    *(unsigned*)(Sbf + (size_t)n * D + c2) = pk;
}

// Node update on MFMA + residual + LayerNorm; optional fused next-layer P-GEMM;
// fused pooling accumulation on the last layer (write_f32).
__global__ __launch_bounds__(256, 3) void node_mfma_kernel(
    const u16* __restrict__ hbf, const u16* __restrict__ Sbf,
    const int* __restrict__ hist,
    const u16* __restrict__ NW1T, const float* __restrict__ ub1,
    const float* __restrict__ nb2p,
    const u16* __restrict__ W2T, const float* __restrict__ b2,
    const float* __restrict__ gamma, const float* __restrict__ beta,
    float* __restrict__ hidden_out, u16* __restrict__ hbf_out,
    const u16* __restrict__ PWTnext, u16* __restrict__ Pout, int write_f32,
    const int* __restrict__ batch, float* __restrict__ pooled)
{
    __shared__ u16 sA[64 * 264];
    __shared__ u16 sH1[64 * 136];
    __shared__ float s_cnt[64];
    __shared__ int s_b[64];
    float* sR = (float*)sA;
    const int tid = threadIdx.x;
    const int n0 = blockIdx.x * 64;

    if (tid < 64) {
        int n = n0 + tid;
        s_b[tid] = (write_f32 && n < NN) ? batch[n] : -1;
        if (n >= NN) n = NN - 1;
        s_cnt[tid] = (float)hist[n];
    }
    {   // stage A = [hbf | Sbf] (both bf16): 32 uint4 chunks/row, 8 per thread
        const int e = tid >> 2, q = tid & 3;
        int n = n0 + e; if (n >= NN) n = NN - 1;
        const uint4* hs = (const uint4*)(hbf + (size_t)n * D);
        const uint4* ss = (const uint4*)(Sbf + (size_t)n * D);
        uint4* ar = (uint4*)(sA + e * 264);
#pragma unroll
        for (int c = 0; c < 8; ++c) {
            int cc = q * 8 + c;
            ar[cc] = (cc < 16) ? hs[cc] : ss[cc - 16];
        }
    }
    __syncthreads();

    const int lane = tid & 63;
    const int l15 = lane & 15;
    const int quad = lane >> 4;
    const int nbase = (tid >> 6) * 32;

    f32x4 acc[4][2];
#pragma unroll
    for (int mt = 0; mt < 4; ++mt)
#pragma unroll
        for (int nt = 0; nt < 2; ++nt) acc[mt][nt] = (f32x4){0.f, 0.f, 0.f, 0.f};

    const u16* bp0 = NW1T + (size_t)(nbase + l15) * 256 + quad * 8;
    const u16* bp1 = bp0 + 16 * 256;
#pragma unroll
    for (int kb = 0; kb < 256; kb += 32) {
        bf16x8 bf0 = *(const bf16x8*)(bp0 + kb);
        bf16x8 bf1 = *(const bf16x8*)(bp1 + kb);
#pragma unroll
        for (int mt = 0; mt < 4; ++mt) {
            bf16x8 af = *(const bf16x8*)(sA + (mt * 16 + l15) * 264 + quad * 8 + kb);
            acc[mt][0] = __builtin_amdgcn_mfma_f32_16x16x32_bf16(af, bf0, acc[mt][0], 0, 0, 0);
            acc[mt][1] = __builtin_amdgcn_mfma_f32_16x16x32_bf16(af, bf1, acc[mt][1], 0, 0, 0);
        }
    }

    // epilogue 1: + ub1 + cnt*b2'; gelu -> sH1
#pragma unroll
    for (int mt = 0; mt < 4; ++mt)
#pragma unroll
        for (int nt = 0; nt < 2; ++nt) {
            const int col = nbase + nt * 16 + l15;
            const float bb = ub1[col];
            const float bp = nb2p[col];
#pragma unroll
            for (int r = 0; r < 4; ++r) {
                const int row = mt * 16 + quad * 4 + r;
                float v = acc[mt][nt][r] + bb + s_cnt[row] * bp;
                sH1[row * 136 + col] = f2bf(gelu_f(v));
            }
        }
    __syncthreads();

    f32x4 acc2[4][2];
#pragma unroll
    for (int mt = 0; mt < 4; ++mt)
#pragma unroll
        for (int nt = 0; nt < 2; ++nt) acc2[mt][nt] = (f32x4){0.f, 0.f, 0.f, 0.f};

    const u16* cp0 = W2T + (size_t)(nbase + l15) * 128 + quad * 8;
    const u16* cp1 = cp0 + 16 * 128;
#pragma unroll
    for (int kb = 0; kb < 128; kb += 32) {
        bf16x8 bf0 = *(const bf16x8*)(cp0 + kb);
        bf16x8 bf1 = *(const bf16x8*)(cp1 + kb);
#pragma unroll
        for (int mt = 0; mt < 4; ++mt) {
            bf16x8 af = *(const bf16x8*)(sH1 + (mt * 16 + l15) * 136 + quad * 8 + kb);
            acc2[mt][0] = __builtin_amdgcn_mfma_f32_16x16x32_bf16(af, bf0, acc2[mt][0], 0, 0, 0);
            acc2[mt][1] = __builtin_amdgcn_mfma_f32_16x16x32_bf16(af, bf1, acc2[mt][1], 0, 0, 0);
        }
    }

    // r = hbf + u -> sR (fp32)
#pragma unroll
    for (int mt = 0; mt < 4; ++mt)
#pragma unroll
        for (int nt = 0; nt < 2; ++nt) {
            const int col = nbase + nt * 16 + l15;
            const float bb = b2[col];
#pragma unroll
            for (int r = 0; r < 4; ++r) {
                const int row = mt * 16 + quad * 4 + r;
                int n = n0 + row; if (n >= NN) n = NN - 1;
                float h = __uint_as_float((unsigned)hbf[(size_t)n * D + col] << 16);
                sR[row * 132 + col] = acc2[mt][nt][r] + bb + h;
            }
        }
    __syncthreads();   // GEMM2's sH1 reads done; sR ready

    // LayerNorm: 4 threads/node, 32 cols each; bf16 -> sH1, f32 -> sR (if needed)
    {
        const int e = tid >> 2, t4 = tid & 3;
        float* rr = sR + e * 132 + t4 * 32;
        float s1 = 0.f, s2 = 0.f;
        float4 v[8];
#pragma unroll
        for (int i = 0; i < 8; ++i) {
            v[i] = *(const float4*)(rr + i * 4);
            s1 += v[i].x + v[i].y + v[i].z + v[i].w;
            s2 += v[i].x * v[i].x + v[i].y * v[i].y + v[i].z * v[i].z + v[i].w * v[i].w;
        }
        s1 += __shfl_xor(s1, 1); s2 += __shfl_xor(s2, 1);
        s1 += __shfl_xor(s1, 2); s2 += __shfl_xor(s2, 2);
        const float mean = s1 * (1.f / 128.f);
        const float var = s2 * (1.f / 128.f) - mean * mean;
        const float rs = rsqrtf(var + LN_EPS);
#pragma unroll
        for (int i = 0; i < 8; ++i) {
            const float4 g = *(const float4*)(gamma + t4 * 32 + i * 4);
            const float4 be = *(const float4*)(beta + t4 * 32 + i * 4);
            float4 o;
            o.x = (v[i].x - mean) * rs * g.x + be.x;
            o.y = (v[i].y - mean) * rs * g.y + be.y;
            o.z = (v[i].z - mean) * rs * g.z + be.z;
            o.w = (v[i].w - mean) * rs * g.w + be.w;
            uint2 pk;
            pk.x = (unsigned)f2bf(o.x) | ((unsigned)f2bf(o.y) << 16);
            pk.y = (unsigned)f2bf(o.z) | ((unsigned)f2bf(o.w) << 16);
            *(uint2*)(sH1 + e * 136 + t4 * 32 + i * 4) = pk;
            if (write_f32) *(float4*)(rr + i * 4) = o;   // stage normalized f32
        }
    }
    __syncthreads();

    // cooperative coalesced stores
    {
        const int e = tid >> 2, q = tid & 3;
        const int n = n0 + e;
        if (n < NN) {
            uint4* hp = (uint4*)(hbf_out + (size_t)n * D);       // 16 chunks/row
            const u16* sh = sH1 + e * 136;
#pragma unroll
            for (int c = 0; c < 4; ++c) hp[q + c * 4] = *(const uint4*)(sh + (q + c * 4) * 8);
            if (write_f32) {
                float4* op = (float4*)(hidden_out + (size_t)n * D);  // 32 chunks/row
                const float* sr = sR + e * 132;
#pragma unroll
                for (int c = 0; c < 8; ++c) op[q + c * 4] = *(const float4*)(sr + (q + c * 4) * 4);
            }
        }
    }

    // fused pooling accumulation (last layer): run-length over sorted batch
    if (write_f32) {
        const int col = tid & 127, half = tid >> 7;
        const int base = half * 32;
        int cur = s_b[base];
        float acc_p = 0.f;
        for (int i = 0; i < 32; ++i) {
            int b = s_b[base + i];
            if (b < 0) break;
            if (b != cur) { atomicAdd(&pooled[cur * D + col], acc_p); cur = b; acc_p = 0.f; }
            acc_p += sR[(base + i) * 132 + col];
        }
        if (cur >= 0) atomicAdd(&pooled[cur * D + col], acc_p);
    }

    // fused next-layer projection: P = h_new @ PWTnext  (M=64, K=128, N=256)
    if (PWTnext) {
        const int nbase4 = (tid >> 6) * 64;
        f32x4 accp[4][4];
#pragma unroll
        for (int mt = 0; mt < 4; ++mt)
#pragma unroll
            for (int nt = 0; nt < 4; ++nt) accp[mt][nt] = (f32x4){0.f, 0.f, 0.f, 0.f};

#pragma unroll
        for (int kb = 0; kb < 128; kb += 32) {
            bf16x8 bf[4];
#pragma unroll
            for (int nt = 0; nt < 4; ++nt)
                bf[nt] = *(const bf16x8*)(PWTnext + (size_t)(nbase4 + nt * 16 + l15) * 128 + quad * 8 + kb);
#pragma unroll
            for (int mt = 0; mt < 4; ++mt) {
                bf16x8 af = *(const bf16x8*)(sH1 + (mt * 16 + l15) * 136 + quad * 8 + kb);
#pragma unroll
                for (int nt = 0; nt < 4; ++nt)
                    accp[mt][nt] = __builtin_amdgcn_mfma_f32_16x16x32_bf16(af, bf[nt], accp[mt][nt], 0, 0, 0);
            }
        }
        __syncthreads();   // sR/sA reads done before sP overwrite
        u16* sP = sA;      // reuse as u16 64x264
#pragma unroll
        for (int mt = 0; mt < 4; ++mt)
#pragma unroll
            for (int nt = 0; nt < 4; ++nt) {
                const int col = nbase4 + nt * 16 + l15;
#pragma unroll
                for (int r = 0; r < 4; ++r)
                    sP[(mt * 16 + quad * 4 + r) * 264 + col] = f2bf(accp[mt][nt][r]);
            }
        __syncthreads();
        const int e = tid >> 2, q = tid & 3;
        const int n = n0 + e;
        if (n < NN) {
            uint4* op = (uint4*)(Pout + (size_t)n * 256);        // 32 chunks/row
            const u16* sp = sP + e * 264;
#pragma unroll
            for (int c = 0; c < 8; ++c) op[q + c * 4] = *(const uint4*)(sp + (q + c * 4) * 8);
        }
    }
}

// ---------------- pooling tail ----------------
__global__ __launch_bounds__(256) void count_kernel(
    const int* __restrict__ batch, float* __restrict__ counts)
{
    int t = blockIdx.x * 256 + threadIdx.x;
    const int chunk = (NN + 8191) / 8192;
    int beg = t * chunk, end = beg + chunk;
    if (end > NN) end = NN;
    if (beg >= NN) return;
    int cur = batch[beg];
    float cnt = 0.f;
    for (int i = beg; i < end; ++i) {
        int b = batch[i];
        if (b != cur) { atomicAdd(&counts[cur], cnt); cur = b; cnt = 0.f; }
        cnt += 1.f;
    }
    atomicAdd(&counts[cur], cnt);
}

__global__ __launch_bounds__(256) void pool_div_kernel(
    float* __restrict__ pooled, const float* __restrict__ counts)
{
    int i = blockIdx.x * 256 + threadIdx.x;
    pooled[i] /= fmaxf(counts[i >> 7], 1.0f);
}

extern "C" void kernel_launch(void* const* d_in, const int* in_sizes, int n_in,
                              void* d_out, int out_size, void* d_ws, size_t ws_size,
                              hipStream_t stream) {
    const float* X     = (const float*)d_in[0];
    const int*   eidx  = (const int*)d_in[1];
    const float* ew    = (const float*)d_in[2];
    const int*   batch = (const int*)d_in[3];
    const float* W_in  = (const float*)d_in[5];
    const float* b_in  = (const float*)d_in[6];
    const float* eW1   = (const float*)d_in[7];
    const float* eb1   = (const float*)d_in[8];
    const float* eW2   = (const float*)d_in[9];
    const float* eb2   = (const float*)d_in[10];
    const float* uW1   = (const float*)d_in[11];
    const float* ub1   = (const float*)d_in[12];
    const float* uW2   = (const float*)d_in[13];
    const float* ub2   = (const float*)d_in[14];
    const float* gamma = (const float*)d_in[15];
    const float* beta  = (const float*)d_in[16];

    float* out_hidden = (float*)d_out;
    float* out_pooled = out_hidden + (size_t)NN * D;

    u16*   hbf  = (u16*)d_ws;                                  // N*128 bf16
    u16*   P    = hbf + (size_t)NN * D;                        // N*256 bf16
    u16*   Sbf  = P + (size_t)NN * 256;                        // N*128 bf16
    u16*   PWT  = Sbf + (size_t)NN * D;                        // NL*256*128
    u16*   NW1T = PWT + (size_t)NL * 256 * 128;                // NL*128*256
    u16*   uW2T = NW1T + (size_t)NL * 128 * 256;               // NL*128*128
    float* nb2p = (float*)(uW2T + (size_t)NL * 128 * 128);     // NL*128
    int*   hist    = (int*)(nb2p + (size_t)NL * 128);
    int*   row_ptr = hist + NN;                                // NN+1 ints
    int*   cursor  = row_ptr + NN + 1;
    int*   bsum    = cursor + NN;                              // SCAN_BLOCKS
    int*   boff    = bsum + SCAN_BLOCKS;                       // SCAN_BLOCKS
    int*   sSrc    = boff + SCAN_BLOCKS;
    float* sEw     = (float*)(sSrc + NE);
    float* counts  = sEw + NE;

    const int* src = eidx;
    const int* dst = eidx + NE;

    // CSR build (parallel 2-level scan)
    hipMemsetAsync(hist, 0, (size_t)NN * sizeof(int), stream);
    hist_kernel<<<NE / 256, 256, 0, stream>>>(dst, hist);
    bsum_kernel<<<SCAN_BLOCKS, 256, 0, stream>>>(hist, bsum);
    bscan_kernel<<<1, 256, 0, stream>>>(bsum, boff);
    emit_kernel<<<SCAN_BLOCKS, 256, 0, stream>>>(hist, boff, row_ptr, cursor);
    scatter_kernel<<<NE / 256, 256, 0, stream>>>(src, dst, ew, cursor, sSrc, sEw);

    // weight prep
    transpose_all_kernel<<<4 * 192, 256, 0, stream>>>(eW1, uW1, uW2, PWT, NW1T, uW2T);
    w2p_kernel<<<192, 256, 0, stream>>>(eW2, uW1, NW1T);
    b2p_kernel<<<NL, 128, 0, stream>>>(eb2, uW1, nb2p);

    input_proj_kernel<<<(NN * D) / 256, 256, 0, stream>>>(X, W_in, b_in, hbf);

    // pooling buffers ready before the fused last-layer accumulation
    hipMemsetAsync(out_pooled, 0, (size_t)NG * D * sizeof(float), stream);
    hipMemsetAsync(counts, 0, (size_t)NG * sizeof(float), stream);
    count_kernel<<<32, 256, 0, stream>>>(batch, counts);

    const int nblk = (NN + 63) / 64;
    proj_kernel<<<nblk, 256, 0, stream>>>(hbf, PWT, P);   // layer-0 P
    for (int l = 0; l < NL; ++l) {
        edge_csr_kernel<<<(NN * 64 + 255) / 256, 256, 0, stream>>>(
            P, sSrc, sEw, row_ptr,
            eW1 + (size_t)l * 257 * 128 + 256 * 128,
            eb1 + (size_t)l * D, Sbf);
        const u16* pwt_next = (l < NL - 1) ? (PWT + (size_t)(l + 1) * 256 * 128) : nullptr;
        node_mfma_kernel<<<nblk, 256, 0, stream>>>(
            hbf, Sbf, hist,
            NW1T + (size_t)l * 128 * 256, ub1 + (size_t)l * D, nb2p + (size_t)l * D,
            uW2T + (size_t)l * 128 * 128, ub2 + (size_t)l * D,
            gamma + (size_t)l * D, beta + (size_t)l * D,
            out_hidden, hbf, pwt_next, P, (l == NL - 1) ? 1 : 0,
            batch, out_pooled);
    }

    pool_div_kernel<<<(NG * D) / 256, 256, 0, stream>>>(out_pooled, counts);
}

// Round 12
// 588.201 us; speedup vs baseline: 1.1337x; 1.0449x over previous
//
#include <hip/hip_runtime.h>
#include <math.h>

#define NN 50000
#define NE 800000
#define DIN 32
#define D 128
#define NL 3
#define NG 64
#define LN_EPS 1e-5f
#define SCAN_BLOCKS 196   // ceil(NN/256)

typedef unsigned short u16;
typedef __bf16 bf16x8 __attribute__((ext_vector_type(8)));
typedef float f32x4 __attribute__((ext_vector_type(4)));

__device__ __forceinline__ float gelu_f(float x) {
    return 0.5f * x * (1.0f + erff(x * 0.70710678118654752f));
}

// tanh-approx gelu, all-native: 7 HW ops, no div sequence
__device__ __forceinline__ float gelu_fast(float x) {
    float u = x * x;
    float z = x * fmaf(-0.1029432f, u, -2.3022082f);
    float e = __builtin_amdgcn_exp2f(z);
    float s = __builtin_amdgcn_rcpf(1.0f + e);
    return x * s;
}

__device__ __forceinline__ u16 f2bf(float x) {
    unsigned int u = __float_as_uint(x);
    u += 0x7fffu + ((u >> 16) & 1u);
    return (u16)(u >> 16);
}

// ---------------- CSR build: hist + 2-level scan + scatter ----------------
__global__ __launch_bounds__(256) void hist_kernel(
    const int* __restrict__ dst, int* __restrict__ hist)
{
    int e = blockIdx.x * 256 + threadIdx.x;
    atomicAdd(&hist[dst[e]], 1);
}

__global__ __launch_bounds__(256) void bsum_kernel(
    const int* __restrict__ hist, int* __restrict__ bsum)
{
    __shared__ int red[256];
    int i = blockIdx.x * 256 + threadIdx.x;
    red[threadIdx.x] = (i < NN) ? hist[i] : 0;
    __syncthreads();
    for (int off = 128; off > 0; off >>= 1) {
        if (threadIdx.x < off) red[threadIdx.x] += red[threadIdx.x + off];
        __syncthreads();
    }
    if (threadIdx.x == 0) bsum[blockIdx.x] = red[0];
}

__global__ __launch_bounds__(256) void bscan_kernel(
    const int* __restrict__ bsum, int* __restrict__ boff)
{
    __shared__ int sc[256];
    const int t = threadIdx.x;
    int orig = (t < SCAN_BLOCKS) ? bsum[t] : 0;
    sc[t] = orig;
    __syncthreads();
    for (int off = 1; off < 256; off <<= 1) {
        int v = (t >= off) ? sc[t - off] : 0;
        __syncthreads();
        sc[t] += v;
        __syncthreads();
    }
    if (t < SCAN_BLOCKS) boff[t] = sc[t] - orig;   // exclusive
}

__global__ __launch_bounds__(256) void emit_kernel(
    const int* __restrict__ hist, const int* __restrict__ boff,
    int* __restrict__ row_ptr, int* __restrict__ cursor)
{
    __shared__ int sc[256];
    const int t = threadIdx.x;
    const int i = blockIdx.x * 256 + t;
    int orig = (i < NN) ? hist[i] : 0;
    sc[t] = orig;
    __syncthreads();
    for (int off = 1; off < 256; off <<= 1) {
        int v = (t >= off) ? sc[t - off] : 0;
        __syncthreads();
        sc[t] += v;
        __syncthreads();
    }
    if (i < NN) {
        int ex = sc[t] - orig + boff[blockIdx.x];
        row_ptr[i] = ex;
        cursor[i] = ex;
    }
    if (i == 0) row_ptr[NN] = NE;
}

__global__ __launch_bounds__(256) void scatter_kernel(
    const int* __restrict__ src, const int* __restrict__ dst,
    const float* __restrict__ ew, int* __restrict__ cursor,
    int* __restrict__ sSrc, float* __restrict__ sEw)
{
    int e = blockIdx.x * 256 + threadIdx.x;
    int d = dst[e];
    int pos = atomicAdd(&cursor[d], 1);
    sSrc[pos] = src[e];
    sEw[pos] = ew[e];
}

// ---------------- input projection: 64 nodes/block, LDS-staged in+out ----------------
__global__ __launch_bounds__(256) void input_proj_kernel(
    const float* __restrict__ X, const float* __restrict__ W,
    const float* __restrict__ b, u16* __restrict__ hbf)
{
    __shared__ float sW[DIN * D];   // 16 KB; reused as u16 out-stage after compute
    __shared__ float sX[64 * DIN];  // 8 KB
    const int tid = threadIdx.x;
    const int n0 = blockIdx.x * 64;

    for (int i = tid; i < DIN * D; i += 256) sW[i] = W[i];
    {   // stage 64 rows of X (guard the ragged last block)
        const float4* xs = (const float4*)(X + (size_t)n0 * DIN);
        float4* xd = (float4*)sX;
#pragma unroll
        for (int c = tid; c < 512; c += 256) {          // 8 float4 per row
            int row = c >> 3;
            xd[c] = (n0 + row < NN) ? xs[c] : (float4){0.f, 0.f, 0.f, 0.f};
        }
    }
    __syncthreads();

    const int e = tid >> 2, q = tid & 3;   // node-in-block, col quad
    float x[DIN];
#pragma unroll
    for (int k = 0; k < DIN; ++k) x[k] = sX[e * DIN + k];

    // thread owns col-chunks {q + cg*4 : cg<8} (float4 chunks) -> contiguous 64B per quad
    uint2 outpk[8];
    const float4* sW4 = (const float4*)sW;
#pragma unroll
    for (int cg = 0; cg < 8; ++cg) {
        const int ch = q + cg * 4;                     // float4 chunk in 0..31
        float4 acc = *(const float4*)(b + ch * 4);
#pragma unroll
        for (int k = 0; k < DIN; ++k) {
            float4 w = sW4[k * 32 + ch];
            acc.x = fmaf(x[k], w.x, acc.x);
            acc.y = fmaf(x[k], w.y, acc.y);
            acc.z = fmaf(x[k], w.z, acc.z);
            acc.w = fmaf(x[k], w.w, acc.w);
        }
        uint2 pk;
        pk.x = (unsigned)f2bf(gelu_f(acc.x)) | ((unsigned)f2bf(gelu_f(acc.y)) << 16);
        pk.y = (unsigned)f2bf(gelu_f(acc.z)) | ((unsigned)f2bf(gelu_f(acc.w)) << 16);
        outpk[cg] = pk;
    }
    __syncthreads();   // all sW reads done -> reuse as out-stage

    u16* sO = (u16*)sW;  // 64 x 128 u16 = 16 KB
#pragma unroll
    for (int cg = 0; cg < 8; ++cg)
        *(uint2*)(sO + e * D + (q + cg * 4) * 4) = outpk[cg];
    __syncthreads();

    {   // cooperative full-sector store: 4 threads/row x 4 uint4
        const int n = n0 + e;
        if (n < NN) {
            uint4* hp = (uint4*)(hbf + (size_t)n * D);
            const u16* so = sO + e * D;
#pragma unroll
            for (int c = 0; c < 4; ++c) hp[q + c * 4] = *(const uint4*)(so + (q + c * 4) * 8);
        }
    }
}

// merged 4-region transpose: dst[n*dstRS + k] = bf16(src[k*128 + n]) per region
__global__ __launch_bounds__(256) void transpose_all_kernel(
    const float* __restrict__ eW1, const float* __restrict__ uW1,
    const float* __restrict__ uW2,
    u16* __restrict__ PWT, u16* __restrict__ NW1T, u16* __restrict__ uW2T)
{
    const int region = blockIdx.x / 192;
    int i = (blockIdx.x - region * 192) * 256 + threadIdx.x;   // 0..49151 (NL*16384)
    int l = i / 16384;
    int r = i - l * 16384;
    int n = r >> 7, k = r & 127;
    const float* srcp; u16* dstp; int srcLS, dstLS, dstRS, srcOff = 0, dstOff = 0;
    if (region == 0)      { srcp = eW1; dstp = PWT;  srcLS = 257 * 128; dstLS = 256 * 128; dstRS = 128; }
    else if (region == 1) { srcp = eW1; dstp = PWT;  srcLS = 257 * 128; dstLS = 256 * 128; dstRS = 128; srcOff = 128 * 128; dstOff = 128 * 128; }
    else if (region == 2) { srcp = uW1; dstp = NW1T; srcLS = 256 * 128; dstLS = 128 * 256; dstRS = 256; }
    else                  { srcp = uW2; dstp = uW2T; srcLS = 128 * 128; dstLS = 128 * 128; dstRS = 128; }
    dstp[(size_t)l * dstLS + dstOff + (size_t)n * dstRS + k] =
        f2bf(srcp[(size_t)l * srcLS + srcOff + (size_t)k * 128 + n]);
}

// NW1T[l][n][128+k] = bf16( sum_j eW2[l][k][j] * uW1[l][128+j][n] )
__global__ __launch_bounds__(256) void w2p_kernel(
    const float* __restrict__ eW2, const float* __restrict__ uW1,
    u16* __restrict__ NW1T)
{
    int i = blockIdx.x * 256 + threadIdx.x;       // NL*128*128
    int l = i / 16384;
    int r = i - l * 16384;
    int n = r >> 7, k = r & 127;
    const float* w2row = eW2 + (size_t)l * 16384 + k * 128;
    const float* u1col = uW1 + (size_t)l * 32768 + 128 * 128 + n;
    float s = 0.f;
#pragma unroll 4
    for (int j = 0; j < 128; ++j) s = fmaf(w2row[j], u1col[j * 128], s);
    NW1T[(size_t)l * 32768 + n * 256 + 128 + k] = f2bf(s);
}

// nb2p[l][n] = sum_j eb2[l][j] * uW1[l][128+j][n]
__global__ __launch_bounds__(128) void b2p_kernel(
    const float* __restrict__ eb2, const float* __restrict__ uW1,
    float* __restrict__ nb2p)
{
    int l = blockIdx.x, n = threadIdx.x;
    const float* b2r = eb2 + l * 128;
    const float* u1col = uW1 + (size_t)l * 32768 + 128 * 128 + n;
    float s = 0.f;
#pragma unroll 4
    for (int j = 0; j < 128; ++j) s = fmaf(b2r[j], u1col[j * 128], s);
    nb2p[l * 128 + n] = s;
}

// P[n][0:256] = hbf[n] @ [W1a | W1b]  (layer-0 only) — LDS-coalesced stores
__global__ __launch_bounds__(256) void proj_kernel(
    const u16* __restrict__ hbf, const u16* __restrict__ PWT,
    u16* __restrict__ P)
{
    __shared__ u16 sA[64 * 136];
    __shared__ u16 sP[64 * 264];
    const int tid = threadIdx.x;
    const int n0 = blockIdx.x * 64;
    {
        const int e = tid >> 2, q = tid & 3;
        int n = n0 + e; if (n >= NN) n = NN - 1;
        const uint4* hs = (const uint4*)(hbf + (size_t)n * D);
        uint4* ar = (uint4*)(sA + e * 136);
#pragma unroll
        for (int c = 0; c < 4; ++c) ar[q * 4 + c] = hs[q * 4 + c];
    }
    __syncthreads();

    const int lane = tid & 63;
    const int l15 = lane & 15;
    const int quad = lane >> 4;
    const int nbase = (tid >> 6) * 64;

    f32x4 acc[4][4];
#pragma unroll
    for (int mt = 0; mt < 4; ++mt)
#pragma unroll
        for (int nt = 0; nt < 4; ++nt) acc[mt][nt] = (f32x4){0.f, 0.f, 0.f, 0.f};

#pragma unroll
    for (int kb = 0; kb < 128; kb += 32) {
        bf16x8 bf[4];
#pragma unroll
        for (int nt = 0; nt < 4; ++nt)
            bf[nt] = *(const bf16x8*)(PWT + (size_t)(nbase + nt * 16 + l15) * 128 + quad * 8 + kb);
#pragma unroll
        for (int mt = 0; mt < 4; ++mt) {
            bf16x8 af = *(const bf16x8*)(sA + (mt * 16 + l15) * 136 + quad * 8 + kb);
#pragma unroll
            for (int nt = 0; nt < 4; ++nt)
                acc[mt][nt] = __builtin_amdgcn_mfma_f32_16x16x32_bf16(af, bf[nt], acc[mt][nt], 0, 0, 0);
        }
    }

#pragma unroll
    for (int mt = 0; mt < 4; ++mt)
#pragma unroll
        for (int nt = 0; nt < 4; ++nt) {
            const int col = nbase + nt * 16 + l15;
#pragma unroll
            for (int r = 0; r < 4; ++r)
                sP[(mt * 16 + quad * 4 + r) * 264 + col] = f2bf(acc[mt][nt][r]);
        }
    __syncthreads();
    {
        const int e = tid >> 2, q = tid & 3;
        const int n = n0 + e;
        if (n < NN) {
            uint4* op = (uint4*)(P + (size_t)n * 256);
            const u16* sp = sP + e * 264;
#pragma unroll
            for (int c = 0; c < 8; ++c) op[q + c * 4] = *(const uint4*)(sp + (q + c * 4) * 8);
        }
    }
}

// CSR edge pass: one wave per dst node, lane owns 2 cols. Zero atomics.
__global__ __launch_bounds__(256) void edge_csr_kernel(
    const u16* __restrict__ P, const int* __restrict__ sSrc,
    const float* __restrict__ sEw, const int* __restrict__ row_ptr,
    const float* __restrict__ W1last, const float* __restrict__ b1,
    u16* __restrict__ Sbf)
{
    const int n = (blockIdx.x * 256 + threadIdx.x) >> 6;
    if (n >= NN) return;
    const int lane = threadIdx.x & 63;
    const int c2 = lane * 2;

    const float wl0 = W1last[c2], wl1 = W1last[c2 + 1];
    unsigned p2 = *(const unsigned*)(P + (size_t)n * 256 + 128 + c2);
    const float t20 = __uint_as_float(p2 << 16) + b1[c2];
    const float t21 = __uint_as_float(p2 & 0xffff0000u) + b1[c2 + 1];

    float a0 = 0.f, a1 = 0.f;
    const int beg = row_ptr[n], end = row_ptr[n + 1];
    int e = beg;
    for (; e + 1 < end; e += 2) {
        const int s0 = sSrc[e], s1 = sSrc[e + 1];
        const float w0 = sEw[e], w1 = sEw[e + 1];
        unsigned pa = *(const unsigned*)(P + (size_t)s0 * 256 + c2);
        unsigned pb = *(const unsigned*)(P + (size_t)s1 * 256 + c2);
        a0 += gelu_fast(__uint_as_float(pa << 16) + t20 + w0 * wl0);
        a1 += gelu_fast(__uint_as_float(pa & 0xffff0000u) + t21 + w0 * wl1);
        a0 += gelu_fast(__uint_as_float(pb << 16) + t20 + w1 * wl0);
        a1 += gelu_fast(__uint_as_float(pb & 0xffff0000u) + t21 + w1 * wl1);
    }
    if (e < end) {
        const int s0 = sSrc[e];
        const float w0 = sEw[e];
        unsigned pa = *(const unsigned*)(P + (size_t)s0 * 256 + c2);
        a0 += gelu_fast(__uint_as_float(pa << 16) + t20 + w0 * wl0);
        a1 += gelu_fast(__uint_as_float(pa & 0xffff0000u) + t21 + w0 * wl1);
    }
    unsigned pk = (unsigned)f2bf(a0) | ((unsigned)f2bf(a1) << 16);
    *(unsigned*)(Sbf + (size_t)n * D + c2) = pk;
}

// Node update on MFMA + residual + LayerNorm; optional fused next-layer P-GEMM;
// fused pooling accumulation on the last layer (write_f32).
__global__ __launch_bounds__(256, 3) void node_mfma_kernel(
    const u16* __restrict__ hbf, const u16* __restrict__ Sbf,
    const int* __restrict__ hist,
    const u16* __restrict__ NW1T, const float* __restrict__ ub1,
    const float* __restrict__ nb2p,
    const u16* __restrict__ W2T, const float* __restrict__ b2,
    const float* __restrict__ gamma, const float* __restrict__ beta,
    float* __restrict__ hidden_out, u16* __restrict__ hbf_out,
    const u16* __restrict__ PWTnext, u16* __restrict__ Pout, int write_f32,
    const int* __restrict__ batch, float* __restrict__ pooled)
{
    __shared__ u16 sA[64 * 264];
    __shared__ u16 sH1[64 * 136];
    __shared__ float s_cnt[64];
    __shared__ int s_b[64];
    float* sR = (float*)sA;
    const int tid = threadIdx.x;
    const int n0 = blockIdx.x * 64;

    if (tid < 64) {
        int n = n0 + tid;
        s_b[tid] = (write_f32 && n < NN) ? batch[n] : -1;
        if (n >= NN) n = NN - 1;
        s_cnt[tid] = (float)hist[n];
    }
    {   // stage A = [hbf | Sbf] (both bf16): 32 uint4 chunks/row, 8 per thread
        const int e = tid >> 2, q = tid & 3;
        int n = n0 + e; if (n >= NN) n = NN - 1;
        const uint4* hs = (const uint4*)(hbf + (size_t)n * D);
        const uint4* ss = (const uint4*)(Sbf + (size_t)n * D);
        uint4* ar = (uint4*)(sA + e * 264);
#pragma unroll
        for (int c = 0; c < 8; ++c) {
            int cc = q * 8 + c;
            ar[cc] = (cc < 16) ? hs[cc] : ss[cc - 16];
        }
    }
    __syncthreads();

    const int lane = tid & 63;
    const int l15 = lane & 15;
    const int quad = lane >> 4;
    const int nbase = (tid >> 6) * 32;

    f32x4 acc[4][2];
#pragma unroll
    for (int mt = 0; mt < 4; ++mt)
#pragma unroll
        for (int nt = 0; nt < 2; ++nt) acc[mt][nt] = (f32x4){0.f, 0.f, 0.f, 0.f};

    const u16* bp0 = NW1T + (size_t)(nbase + l15) * 256 + quad * 8;
    const u16* bp1 = bp0 + 16 * 256;
#pragma unroll
    for (int kb = 0; kb < 256; kb += 32) {
        bf16x8 bf0 = *(const bf16x8*)(bp0 + kb);
        bf16x8 bf1 = *(const bf16x8*)(bp1 + kb);
#pragma unroll
        for (int mt = 0; mt < 4; ++mt) {
            bf16x8 af = *(const bf16x8*)(sA + (mt * 16 + l15) * 264 + quad * 8 + kb);
            acc[mt][0] = __builtin_amdgcn_mfma_f32_16x16x32_bf16(af, bf0, acc[mt][0], 0, 0, 0);
            acc[mt][1] = __builtin_amdgcn_mfma_f32_16x16x32_bf16(af, bf1, acc[mt][1], 0, 0, 0);
        }
    }

    // epilogue 1: + ub1 + cnt*b2'; gelu -> sH1
#pragma unroll
    for (int mt = 0; mt < 4; ++mt)
#pragma unroll
        for (int nt = 0; nt < 2; ++nt) {
            const int col = nbase + nt * 16 + l15;
            const float bb = ub1[col];
            const float bp = nb2p[col];
#pragma unroll
            for (int r = 0; r < 4; ++r) {
                const int row = mt * 16 + quad * 4 + r;
                float v = acc[mt][nt][r] + bb + s_cnt[row] * bp;
                sH1[row * 136 + col] = f2bf(gelu_f(v));
            }
        }
    __syncthreads();

    f32x4 acc2[4][2];
#pragma unroll
    for (int mt = 0; mt < 4; ++mt)
#pragma unroll
        for (int nt = 0; nt < 2; ++nt) acc2[mt][nt] = (f32x4){0.f, 0.f, 0.f, 0.f};

    const u16* cp0 = W2T + (size_t)(nbase + l15) * 128 + quad * 8;
    const u16* cp1 = cp0 + 16 * 128;
#pragma unroll
    for (int kb = 0; kb < 128; kb += 32) {
        bf16x8 bf0 = *(const bf16x8*)(cp0 + kb);
        bf16x8 bf1 = *(const bf16x8*)(cp1 + kb);
#pragma unroll
        for (int mt = 0; mt < 4; ++mt) {
            bf16x8 af = *(const bf16x8*)(sH1 + (mt * 16 + l15) * 136 + quad * 8 + kb);
            acc2[mt][0] = __builtin_amdgcn_mfma_f32_16x16x32_bf16(af, bf0, acc2[mt][0], 0, 0, 0);
            acc2[mt][1] = __builtin_amdgcn_mfma_f32_16x16x32_bf16(af, bf1, acc2[mt][1], 0, 0, 0);
        }
    }

    // r = hbf + u -> sR (fp32)
#pragma unroll
    for (int mt = 0; mt < 4; ++mt)
#pragma unroll
        for (int nt = 0; nt < 2; ++nt) {
            const int col = nbase + nt * 16 + l15;
            const float bb = b2[col];
#pragma unroll
            for (int r = 0; r < 4; ++r) {
                const int row = mt * 16 + quad * 4 + r;
                int n = n0 + row; if (n >= NN) n = NN - 1;
                float h = __uint_as_float((unsigned)hbf[(size_t)n * D + col] << 16);
                sR[row * 132 + col] = acc2[mt][nt][r] + bb + h;
            }
        }
    __syncthreads();   // GEMM2's sH1 reads done; sR ready

    // LayerNorm: 4 threads/node, 32 cols each; bf16 -> sH1, f32 -> sR (if needed)
    {
        const int e = tid >> 2, t4 = tid & 3;
        float* rr = sR + e * 132 + t4 * 32;
        float s1 = 0.f, s2 = 0.f;
        float4 v[8];
#pragma unroll
        for (int i = 0; i < 8; ++i) {
            v[i] = *(const float4*)(rr + i * 4);
            s1 += v[i].x + v[i].y + v[i].z + v[i].w;
            s2 += v[i].x * v[i].x + v[i].y * v[i].y + v[i].z * v[i].z + v[i].w * v[i].w;
        }
        s1 += __shfl_xor(s1, 1); s2 += __shfl_xor(s2, 1);
        s1 += __shfl_xor(s1, 2); s2 += __shfl_xor(s2, 2);
        const float mean = s1 * (1.f / 128.f);
        const float var = s2 * (1.f / 128.f) - mean * mean;
        const float rs = rsqrtf(var + LN_EPS);
#pragma unroll
        for (int i = 0; i < 8; ++i) {
            const float4 g = *(const float4*)(gamma + t4 * 32 + i * 4);
            const float4 be = *(const float4*)(beta + t4 * 32 + i * 4);
            float4 o;
            o.x = (v[i].x - mean) * rs * g.x + be.x;
            o.y = (v[i].y - mean) * rs * g.y + be.y;
            o.z = (v[i].z - mean) * rs * g.z + be.z;
            o.w = (v[i].w - mean) * rs * g.w + be.w;
            uint2 pk;
            pk.x = (unsigned)f2bf(o.x) | ((unsigned)f2bf(o.y) << 16);
            pk.y = (unsigned)f2bf(o.z) | ((unsigned)f2bf(o.w) << 16);
            *(uint2*)(sH1 + e * 136 + t4 * 32 + i * 4) = pk;
            if (write_f32) *(float4*)(rr + i * 4) = o;   // stage normalized f32
        }
    }
    __syncthreads();

    // cooperative coalesced stores
    {
        const int e = tid >> 2, q = tid & 3;
        const int n = n0 + e;
        if (n < NN) {
            uint4* hp = (uint4*)(hbf_out + (size_t)n * D);       // 16 chunks/row
            const u16* sh = sH1 + e * 136;
#pragma unroll
            for (int c = 0; c < 4; ++c) hp[q + c * 4] = *(const uint4*)(sh + (q + c * 4) * 8);
            if (write_f32) {
                float4* op = (float4*)(hidden_out + (size_t)n * D);  // 32 chunks/row
                const float* sr = sR + e * 132;
#pragma unroll
                for (int c = 0; c < 8; ++c) op[q + c * 4] = *(const float4*)(sr + (q + c * 4) * 4);
            }
        }
    }

    // fused pooling accumulation (last layer): run-length over sorted batch
    if (write_f32) {
        const int col = tid & 127, half = tid >> 7;
        const int base = half * 32;
        int cur = s_b[base];
        float acc_p = 0.f;
        for (int i = 0; i < 32; ++i) {
            int b = s_b[base + i];
            if (b < 0) break;
            if (b != cur) { atomicAdd(&pooled[cur * D + col], acc_p); cur = b; acc_p = 0.f; }
            acc_p += sR[(base + i) * 132 + col];
        }
        if (cur >= 0) atomicAdd(&pooled[cur * D + col], acc_p);
    }

    // fused next-layer projection: P = h_new @ PWTnext  (M=64, K=128, N=256)
    if (PWTnext) {
        const int nbase4 = (tid >> 6) * 64;
        f32x4 accp[4][4];
#pragma unroll
        for (int mt = 0; mt < 4; ++mt)
#pragma unroll
            for (int nt = 0; nt < 4; ++nt) accp[mt][nt] = (f32x4){0.f, 0.f, 0.f, 0.f};

#pragma unroll
        for (int kb = 0; kb < 128; kb += 32) {
            bf16x8 bf[4];
#pragma unroll
            for (int nt = 0; nt < 4; ++nt)
                bf[nt] = *(const bf16x8*)(PWTnext + (size_t)(nbase4 + nt * 16 + l15) * 128 + quad * 8 + kb);
#pragma unroll
            for (int mt = 0; mt < 4; ++mt) {
                bf16x8 af = *(const bf16x8*)(sH1 + (mt * 16 + l15) * 136 + quad * 8 + kb);
#pragma unroll
                for (int nt = 0; nt < 4; ++nt)
                    accp[mt][nt] = __builtin_amdgcn_mfma_f32_16x16x32_bf16(af, bf[nt], accp[mt][nt], 0, 0, 0);
            }
        }
        __syncthreads();   // sR/sA reads done before sP overwrite
        u16* sP = sA;      // reuse as u16 64x264
#pragma unroll
        for (int mt = 0; mt < 4; ++mt)
#pragma unroll
            for (int nt = 0; nt < 4; ++nt) {
                const int col = nbase4 + nt * 16 + l15;
#pragma unroll
                for (int r = 0; r < 4; ++r)
                    sP[(mt * 16 + quad * 4 + r) * 264 + col] = f2bf(accp[mt][nt][r]);
            }
        __syncthreads();
        const int e = tid >> 2, q = tid & 3;
        const int n = n0 + e;
        if (n < NN) {
            uint4* op = (uint4*)(Pout + (size_t)n * 256);        // 32 chunks/row
            const u16* sp = sP + e * 264;
#pragma unroll
            for (int c = 0; c < 8; ++c) op[q + c * 4] = *(const uint4*)(sp + (q + c * 4) * 8);
        }
    }
}

// ---------------- pooling tail ----------------
__global__ __launch_bounds__(256) void count_kernel(
    const int* __restrict__ batch, float* __restrict__ counts)
{
    int t = blockIdx.x * 256 + threadIdx.x;
    const int chunk = (NN + 8191) / 8192;
    int beg = t * chunk, end = beg + chunk;
    if (end > NN) end = NN;
    if (beg >= NN) return;
    int cur = batch[beg];
    float cnt = 0.f;
    for (int i = beg; i < end; ++i) {
        int b = batch[i];
        if (b != cur) { atomicAdd(&counts[cur], cnt); cur = b; cnt = 0.f; }
        cnt += 1.f;
    }
    atomicAdd(&counts[cur], cnt);
}

__global__ __launch_bounds__(256) void pool_div_kernel(
    float* __restrict__ pooled, const float* __restrict__ counts)
{
    int i = blockIdx.x * 256 + threadIdx.x;
    pooled[i] /= fmaxf(counts[i >> 7], 1.0f);
}

extern "C" void kernel_launch(void* const* d_in, const int* in_sizes, int n_in,
                              void* d_out, int out_size, void* d_ws, size_t ws_size,
                              hipStream_t stream) {
    const float* X     = (const float*)d_in[0];
    const int*   eidx  = (const int*)d_in[1];
    const float* ew    = (const float*)d_in[2];
    const int*   batch = (const int*)d_in[3];
    const float* W_in  = (const float*)d_in[5];
    const float* b_in  = (const float*)d_in[6];
    const float* eW1   = (const float*)d_in[7];
    const float* eb1   = (const float*)d_in[8];
    const float* eW2   = (const float*)d_in[9];
    const float* eb2   = (const float*)d_in[10];
    const float* uW1   = (const float*)d_in[11];
    const float* ub1   = (const float*)d_in[12];
    const float* uW2   = (const float*)d_in[13];
    const float* ub2   = (const float*)d_in[14];
    const float* gamma = (const float*)d_in[15];
    const float* beta  = (const float*)d_in[16];

    float* out_hidden = (float*)d_out;
    float* out_pooled = out_hidden + (size_t)NN * D;

    u16*   hbf  = (u16*)d_ws;                                  // N*128 bf16
    u16*   P    = hbf + (size_t)NN * D;                        // N*256 bf16
    u16*   Sbf  = P + (size_t)NN * 256;                        // N*128 bf16
    u16*   PWT  = Sbf + (size_t)NN * D;                        // NL*256*128
    u16*   NW1T = PWT + (size_t)NL * 256 * 128;                // NL*128*256
    u16*   uW2T = NW1T + (size_t)NL * 128 * 256;               // NL*128*128
    float* nb2p = (float*)(uW2T + (size_t)NL * 128 * 128);     // NL*128
    int*   hist    = (int*)(nb2p + (size_t)NL * 128);
    int*   row_ptr = hist + NN;                                // NN+1 ints
    int*   cursor  = row_ptr + NN + 1;
    int*   bsum    = cursor + NN;                              // SCAN_BLOCKS
    int*   boff    = bsum + SCAN_BLOCKS;                       // SCAN_BLOCKS
    int*   sSrc    = boff + SCAN_BLOCKS;
    float* sEw     = (float*)(sSrc + NE);
    float* counts  = sEw + NE;

    const int* src = eidx;
    const int* dst = eidx + NE;

    // CSR build (parallel 2-level scan)
    hipMemsetAsync(hist, 0, (size_t)NN * sizeof(int), stream);
    hist_kernel<<<NE / 256, 256, 0, stream>>>(dst, hist);
    bsum_kernel<<<SCAN_BLOCKS, 256, 0, stream>>>(hist, bsum);
    bscan_kernel<<<1, 256, 0, stream>>>(bsum, boff);
    emit_kernel<<<SCAN_BLOCKS, 256, 0, stream>>>(hist, boff, row_ptr, cursor);
    scatter_kernel<<<NE / 256, 256, 0, stream>>>(src, dst, ew, cursor, sSrc, sEw);

    // weight prep
    transpose_all_kernel<<<4 * 192, 256, 0, stream>>>(eW1, uW1, uW2, PWT, NW1T, uW2T);
    w2p_kernel<<<192, 256, 0, stream>>>(eW2, uW1, NW1T);
    b2p_kernel<<<NL, 128, 0, stream>>>(eb2, uW1, nb2p);

    input_proj_kernel<<<(NN + 63) / 64, 256, 0, stream>>>(X, W_in, b_in, hbf);

    // pooling buffers ready before the fused last-layer accumulation
    hipMemsetAsync(out_pooled, 0, (size_t)NG * D * sizeof(float), stream);
    hipMemsetAsync(counts, 0, (size_t)NG * sizeof(float), stream);
    count_kernel<<<32, 256, 0, stream>>>(batch, counts);

    const int nblk = (NN + 63) / 64;
    proj_kernel<<<nblk, 256, 0, stream>>>(hbf, PWT, P);   // layer-0 P
    for (int l = 0; l < NL; ++l) {
        edge_csr_kernel<<<(NN * 64 + 255) / 256, 256, 0, stream>>>(
            P, sSrc, sEw, row_ptr,
            eW1 + (size_t)l * 257 * 128 + 256 * 128,
            eb1 + (size_t)l * D, Sbf);
        const u16* pwt_next = (l < NL - 1) ? (PWT + (size_t)(l + 1) * 256 * 128) : nullptr;
        node_mfma_kernel<<<nblk, 256, 0, stream>>>(
            hbf, Sbf, hist,
            NW1T + (size_t)l * 128 * 256, ub1 + (size_t)l * D, nb2p + (size_t)l * D,
            uW2T + (size_t)l * 128 * 128, ub2 + (size_t)l * D,
            gamma + (size_t)l * D, beta + (size_t)l * D,
            out_hidden, hbf, pwt_next, P, (l == NL - 1) ? 1 : 0,
            batch, out_pooled);
    }

    pool_div_kernel<<<(NG * D) / 256, 256, 0, stream>>>(out_pooled, counts);
}

// Round 13
// 544.873 us; speedup vs baseline: 1.2239x; 1.0795x over previous
//
#include <hip/hip_runtime.h>
#include <math.h>

#define NN 50000
#define NE 800000
#define DIN 32
#define D 128
#define NL 3
#define NG 64
#define LN_EPS 1e-5f
#define SCAN_BLOCKS 196   // ceil(NN/256)

typedef unsigned short u16;
typedef __bf16 bf16x8 __attribute__((ext_vector_type(8)));
typedef float f32x4 __attribute__((ext_vector_type(4)));

__device__ __forceinline__ float gelu_f(float x) {
    return 0.5f * x * (1.0f + erff(x * 0.70710678118654752f));
}

// tanh-approx gelu, all-native: 7 HW ops, no div sequence
__device__ __forceinline__ float gelu_fast(float x) {
    float u = x * x;
    float z = x * fmaf(-0.1029432f, u, -2.3022082f);
    float e = __builtin_amdgcn_exp2f(z);
    float s = __builtin_amdgcn_rcpf(1.0f + e);
    return x * s;
}

__device__ __forceinline__ u16 f2bf(float x) {
    unsigned int u = __float_as_uint(x);
    u += 0x7fffu + ((u >> 16) & 1u);
    return (u16)(u >> 16);
}

// ---------------- CSR build: hist + 2-level scan + scatter ----------------
__global__ __launch_bounds__(256) void hist_kernel(
    const int* __restrict__ dst, int* __restrict__ hist)
{
    int e = blockIdx.x * 256 + threadIdx.x;
    atomicAdd(&hist[dst[e]], 1);
}

__global__ __launch_bounds__(256) void bsum_kernel(
    const int* __restrict__ hist, int* __restrict__ bsum)
{
    __shared__ int red[256];
    int i = blockIdx.x * 256 + threadIdx.x;
    red[threadIdx.x] = (i < NN) ? hist[i] : 0;
    __syncthreads();
    for (int off = 128; off > 0; off >>= 1) {
        if (threadIdx.x < off) red[threadIdx.x] += red[threadIdx.x + off];
        __syncthreads();
    }
    if (threadIdx.x == 0) bsum[blockIdx.x] = red[0];
}

__global__ __launch_bounds__(256) void bscan_kernel(
    const int* __restrict__ bsum, int* __restrict__ boff)
{
    __shared__ int sc[256];
    const int t = threadIdx.x;
    int orig = (t < SCAN_BLOCKS) ? bsum[t] : 0;
    sc[t] = orig;
    __syncthreads();
    for (int off = 1; off < 256; off <<= 1) {
        int v = (t >= off) ? sc[t - off] : 0;
        __syncthreads();
        sc[t] += v;
        __syncthreads();
    }
    if (t < SCAN_BLOCKS) boff[t] = sc[t] - orig;   // exclusive
}

__global__ __launch_bounds__(256) void emit_kernel(
    const int* __restrict__ hist, const int* __restrict__ boff,
    int* __restrict__ row_ptr, int* __restrict__ cursor)
{
    __shared__ int sc[256];
    const int t = threadIdx.x;
    const int i = blockIdx.x * 256 + t;
    int orig = (i < NN) ? hist[i] : 0;
    sc[t] = orig;
    __syncthreads();
    for (int off = 1; off < 256; off <<= 1) {
        int v = (t >= off) ? sc[t - off] : 0;
        __syncthreads();
        sc[t] += v;
        __syncthreads();
    }
    if (i < NN) {
        int ex = sc[t] - orig + boff[blockIdx.x];
        row_ptr[i] = ex;
        cursor[i] = ex;
    }
    if (i == 0) row_ptr[NN] = NE;
}

// packed edge record: {src byte-row-offset (src*512), ew bits}
__global__ __launch_bounds__(256) void scatter_kernel(
    const int* __restrict__ src, const int* __restrict__ dst,
    const float* __restrict__ ew, int* __restrict__ cursor,
    int2* __restrict__ sEdge)
{
    int e = blockIdx.x * 256 + threadIdx.x;
    int d = dst[e];
    int pos = atomicAdd(&cursor[d], 1);
    int2 v;
    v.x = src[e] << 9;            // row offset in bytes into P (256 u16 = 512 B)
    v.y = __float_as_int(ew[e]);
    sEdge[pos] = v;
}

// ---------------- input projection: 64 nodes/block, LDS-staged in+out ----------------
__global__ __launch_bounds__(256) void input_proj_kernel(
    const float* __restrict__ X, const float* __restrict__ W,
    const float* __restrict__ b, u16* __restrict__ hbf)
{
    __shared__ float sW[DIN * D];   // 16 KB; reused as u16 out-stage after compute
    __shared__ float sX[64 * DIN];  // 8 KB
    const int tid = threadIdx.x;
    const int n0 = blockIdx.x * 64;

    for (int i = tid; i < DIN * D; i += 256) sW[i] = W[i];
    {
        const float4* xs = (const float4*)(X + (size_t)n0 * DIN);
        float4* xd = (float4*)sX;
#pragma unroll
        for (int c = tid; c < 512; c += 256) {
            int row = c >> 3;
            xd[c] = (n0 + row < NN) ? xs[c] : (float4){0.f, 0.f, 0.f, 0.f};
        }
    }
    __syncthreads();

    const int e = tid >> 2, q = tid & 3;
    float x[DIN];
#pragma unroll
    for (int k = 0; k < DIN; ++k) x[k] = sX[e * DIN + k];

    uint2 outpk[8];
    const float4* sW4 = (const float4*)sW;
#pragma unroll
    for (int cg = 0; cg < 8; ++cg) {
        const int ch = q + cg * 4;
        float4 acc = *(const float4*)(b + ch * 4);
#pragma unroll
        for (int k = 0; k < DIN; ++k) {
            float4 w = sW4[k * 32 + ch];
            acc.x = fmaf(x[k], w.x, acc.x);
            acc.y = fmaf(x[k], w.y, acc.y);
            acc.z = fmaf(x[k], w.z, acc.z);
            acc.w = fmaf(x[k], w.w, acc.w);
        }
        uint2 pk;
        pk.x = (unsigned)f2bf(gelu_f(acc.x)) | ((unsigned)f2bf(gelu_f(acc.y)) << 16);
        pk.y = (unsigned)f2bf(gelu_f(acc.z)) | ((unsigned)f2bf(gelu_f(acc.w)) << 16);
        outpk[cg] = pk;
    }
    __syncthreads();

    u16* sO = (u16*)sW;
#pragma unroll
    for (int cg = 0; cg < 8; ++cg)
        *(uint2*)(sO + e * D + (q + cg * 4) * 4) = outpk[cg];
    __syncthreads();

    {
        const int n = n0 + e;
        if (n < NN) {
            uint4* hp = (uint4*)(hbf + (size_t)n * D);
            const u16* so = sO + e * D;
#pragma unroll
            for (int c = 0; c < 4; ++c) hp[q + c * 4] = *(const uint4*)(so + (q + c * 4) * 8);
        }
    }
}

// merged 4-region transpose
__global__ __launch_bounds__(256) void transpose_all_kernel(
    const float* __restrict__ eW1, const float* __restrict__ uW1,
    const float* __restrict__ uW2,
    u16* __restrict__ PWT, u16* __restrict__ NW1T, u16* __restrict__ uW2T)
{
    const int region = blockIdx.x / 192;
    int i = (blockIdx.x - region * 192) * 256 + threadIdx.x;
    int l = i / 16384;
    int r = i - l * 16384;
    int n = r >> 7, k = r & 127;
    const float* srcp; u16* dstp; int srcLS, dstLS, dstRS, srcOff = 0, dstOff = 0;
    if (region == 0)      { srcp = eW1; dstp = PWT;  srcLS = 257 * 128; dstLS = 256 * 128; dstRS = 128; }
    else if (region == 1) { srcp = eW1; dstp = PWT;  srcLS = 257 * 128; dstLS = 256 * 128; dstRS = 128; srcOff = 128 * 128; dstOff = 128 * 128; }
    else if (region == 2) { srcp = uW1; dstp = NW1T; srcLS = 256 * 128; dstLS = 128 * 256; dstRS = 256; }
    else                  { srcp = uW2; dstp = uW2T; srcLS = 128 * 128; dstLS = 128 * 128; dstRS = 128; }
    dstp[(size_t)l * dstLS + dstOff + (size_t)n * dstRS + k] =
        f2bf(srcp[(size_t)l * srcLS + srcOff + (size_t)k * 128 + n]);
}

// NW1T[l][n][128+k] = bf16( sum_j eW2[l][k][j] * uW1[l][128+j][n] )
__global__ __launch_bounds__(256) void w2p_kernel(
    const float* __restrict__ eW2, const float* __restrict__ uW1,
    u16* __restrict__ NW1T)
{
    int i = blockIdx.x * 256 + threadIdx.x;
    int l = i / 16384;
    int r = i - l * 16384;
    int n = r >> 7, k = r & 127;
    const float* w2row = eW2 + (size_t)l * 16384 + k * 128;
    const float* u1col = uW1 + (size_t)l * 32768 + 128 * 128 + n;
    float s = 0.f;
#pragma unroll 4
    for (int j = 0; j < 128; ++j) s = fmaf(w2row[j], u1col[j * 128], s);
    NW1T[(size_t)l * 32768 + n * 256 + 128 + k] = f2bf(s);
}

// nb2p[l][n] = sum_j eb2[l][j] * uW1[l][128+j][n]
__global__ __launch_bounds__(128) void b2p_kernel(
    const float* __restrict__ eb2, const float* __restrict__ uW1,
    float* __restrict__ nb2p)
{
    int l = blockIdx.x, n = threadIdx.x;
    const float* b2r = eb2 + l * 128;
    const float* u1col = uW1 + (size_t)l * 32768 + 128 * 128 + n;
    float s = 0.f;
#pragma unroll 4
    for (int j = 0; j < 128; ++j) s = fmaf(b2r[j], u1col[j * 128], s);
    nb2p[l * 128 + n] = s;
}

// P[n][0:256] = hbf[n] @ [W1a | W1b]  (layer-0 only)
__global__ __launch_bounds__(256) void proj_kernel(
    const u16* __restrict__ hbf, const u16* __restrict__ PWT,
    u16* __restrict__ P)
{
    __shared__ u16 sA[64 * 136];
    __shared__ u16 sP[64 * 264];
    const int tid = threadIdx.x;
    const int n0 = blockIdx.x * 64;
    {
        const int e = tid >> 2, q = tid & 3;
        int n = n0 + e; if (n >= NN) n = NN - 1;
        const uint4* hs = (const uint4*)(hbf + (size_t)n * D);
        uint4* ar = (uint4*)(sA + e * 136);
#pragma unroll
        for (int c = 0; c < 4; ++c) ar[q * 4 + c] = hs[q * 4 + c];
    }
    __syncthreads();

    const int lane = tid & 63;
    const int l15 = lane & 15;
    const int quad = lane >> 4;
    const int nbase = (tid >> 6) * 64;

    f32x4 acc[4][4];
#pragma unroll
    for (int mt = 0; mt < 4; ++mt)
#pragma unroll
        for (int nt = 0; nt < 4; ++nt) acc[mt][nt] = (f32x4){0.f, 0.f, 0.f, 0.f};

#pragma unroll
    for (int kb = 0; kb < 128; kb += 32) {
        bf16x8 bf[4];
#pragma unroll
        for (int nt = 0; nt < 4; ++nt)
            bf[nt] = *(const bf16x8*)(PWT + (size_t)(nbase + nt * 16 + l15) * 128 + quad * 8 + kb);
#pragma unroll
        for (int mt = 0; mt < 4; ++mt) {
            bf16x8 af = *(const bf16x8*)(sA + (mt * 16 + l15) * 136 + quad * 8 + kb);
#pragma unroll
            for (int nt = 0; nt < 4; ++nt)
                acc[mt][nt] = __builtin_amdgcn_mfma_f32_16x16x32_bf16(af, bf[nt], acc[mt][nt], 0, 0, 0);
        }
    }

#pragma unroll
    for (int mt = 0; mt < 4; ++mt)
#pragma unroll
        for (int nt = 0; nt < 4; ++nt) {
            const int col = nbase + nt * 16 + l15;
#pragma unroll
            for (int r = 0; r < 4; ++r)
                sP[(mt * 16 + quad * 4 + r) * 264 + col] = f2bf(acc[mt][nt][r]);
        }
    __syncthreads();
    {
        const int e = tid >> 2, q = tid & 3;
        const int n = n0 + e;
        if (n < NN) {
            uint4* op = (uint4*)(P + (size_t)n * 256);
            const u16* sp = sP + e * 264;
#pragma unroll
            for (int c = 0; c < 8; ++c) op[q + c * 4] = *(const uint4*)(sp + (q + c * 4) * 8);
        }
    }
}

// CSR edge pass: one wave per dst node, lane owns 2 cols. Zero atomics.
// Packed edge records + 32-bit offset gathers + 4x unroll.
__global__ __launch_bounds__(256) void edge_csr_kernel(
    const u16* __restrict__ P, const int2* __restrict__ sEdge,
    const int* __restrict__ row_ptr,
    const float* __restrict__ W1last, const float* __restrict__ b1,
    u16* __restrict__ Sbf)
{
    const int n = (blockIdx.x * 256 + threadIdx.x) >> 6;
    if (n >= NN) return;
    const int lane = threadIdx.x & 63;
    const int c2 = lane * 2;
    const unsigned laneoff = (unsigned)(c2 * 2);   // byte offset of this lane's dword in a P row
    const char* Pb = (const char*)P;

    const float wl0 = W1last[c2], wl1 = W1last[c2 + 1];
    unsigned p2 = *(const unsigned*)(Pb + ((unsigned)n * 512u + 256u + laneoff));
    const float t20 = __uint_as_float(p2 << 16) + b1[c2];
    const float t21 = __uint_as_float(p2 & 0xffff0000u) + b1[c2 + 1];

    float a0 = 0.f, a1 = 0.f;
    const int beg = row_ptr[n];
    const int m = row_ptr[n + 1] - beg;
    const int2* ep = sEdge + beg;
    int i = 0;
    for (; i + 3 < m; i += 4) {            // 4 gathers in flight
        int2 q0 = ep[i], q1 = ep[i + 1], q2 = ep[i + 2], q3 = ep[i + 3];
        unsigned pa = *(const unsigned*)(Pb + ((unsigned)q0.x + laneoff));
        unsigned pb = *(const unsigned*)(Pb + ((unsigned)q1.x + laneoff));
        unsigned pc = *(const unsigned*)(Pb + ((unsigned)q2.x + laneoff));
        unsigned pd = *(const unsigned*)(Pb + ((unsigned)q3.x + laneoff));
        float w0 = __int_as_float(q0.y), w1 = __int_as_float(q1.y);
        float w2 = __int_as_float(q2.y), w3 = __int_as_float(q3.y);
        a0 += gelu_fast(fmaf(w0, wl0, __uint_as_float(pa << 16) + t20));
        a1 += gelu_fast(fmaf(w0, wl1, __uint_as_float(pa & 0xffff0000u) + t21));
        a0 += gelu_fast(fmaf(w1, wl0, __uint_as_float(pb << 16) + t20));
        a1 += gelu_fast(fmaf(w1, wl1, __uint_as_float(pb & 0xffff0000u) + t21));
        a0 += gelu_fast(fmaf(w2, wl0, __uint_as_float(pc << 16) + t20));
        a1 += gelu_fast(fmaf(w2, wl1, __uint_as_float(pc & 0xffff0000u) + t21));
        a0 += gelu_fast(fmaf(w3, wl0, __uint_as_float(pd << 16) + t20));
        a1 += gelu_fast(fmaf(w3, wl1, __uint_as_float(pd & 0xffff0000u) + t21));
    }
    for (; i < m; ++i) {
        int2 q0 = ep[i];
        unsigned pa = *(const unsigned*)(Pb + ((unsigned)q0.x + laneoff));
        float w0 = __int_as_float(q0.y);
        a0 += gelu_fast(fmaf(w0, wl0, __uint_as_float(pa << 16) + t20));
        a1 += gelu_fast(fmaf(w0, wl1, __uint_as_float(pa & 0xffff0000u) + t21));
    }
    unsigned pk = (unsigned)f2bf(a0) | ((unsigned)f2bf(a1) << 16);
    *(unsigned*)(Sbf + (size_t)n * D + c2) = pk;
}

// Node update on MFMA + residual + LayerNorm; optional fused next-layer P-GEMM;
// fused pooling accumulation on the last layer (write_f32).
__global__ __launch_bounds__(256, 3) void node_mfma_kernel(
    const u16* __restrict__ hbf, const u16* __restrict__ Sbf,
    const int* __restrict__ hist,
    const u16* __restrict__ NW1T, const float* __restrict__ ub1,
    const float* __restrict__ nb2p,
    const u16* __restrict__ W2T, const float* __restrict__ b2,
    const float* __restrict__ gamma, const float* __restrict__ beta,
    float* __restrict__ hidden_out, u16* __restrict__ hbf_out,
    const u16* __restrict__ PWTnext, u16* __restrict__ Pout, int write_f32,
    const int* __restrict__ batch, float* __restrict__ pooled)
{
    __shared__ u16 sA[64 * 264];
    __shared__ u16 sH1[64 * 136];
    __shared__ float s_cnt[64];
    __shared__ int s_b[64];
    float* sR = (float*)sA;
    const int tid = threadIdx.x;
    const int n0 = blockIdx.x * 64;

    if (tid < 64) {
        int n = n0 + tid;
        s_b[tid] = (write_f32 && n < NN) ? batch[n] : -1;
        if (n >= NN) n = NN - 1;
        s_cnt[tid] = (float)hist[n];
    }
    {
        const int e = tid >> 2, q = tid & 3;
        int n = n0 + e; if (n >= NN) n = NN - 1;
        const uint4* hs = (const uint4*)(hbf + (size_t)n * D);
        const uint4* ss = (const uint4*)(Sbf + (size_t)n * D);
        uint4* ar = (uint4*)(sA + e * 264);
#pragma unroll
        for (int c = 0; c < 8; ++c) {
            int cc = q * 8 + c;
            ar[cc] = (cc < 16) ? hs[cc] : ss[cc - 16];
        }
    }
    __syncthreads();

    const int lane = tid & 63;
    const int l15 = lane & 15;
    const int quad = lane >> 4;
    const int nbase = (tid >> 6) * 32;

    f32x4 acc[4][2];
#pragma unroll
    for (int mt = 0; mt < 4; ++mt)
#pragma unroll
        for (int nt = 0; nt < 2; ++nt) acc[mt][nt] = (f32x4){0.f, 0.f, 0.f, 0.f};

    const u16* bp0 = NW1T + (size_t)(nbase + l15) * 256 + quad * 8;
    const u16* bp1 = bp0 + 16 * 256;
#pragma unroll
    for (int kb = 0; kb < 256; kb += 32) {
        bf16x8 bf0 = *(const bf16x8*)(bp0 + kb);
        bf16x8 bf1 = *(const bf16x8*)(bp1 + kb);
#pragma unroll
        for (int mt = 0; mt < 4; ++mt) {
            bf16x8 af = *(const bf16x8*)(sA + (mt * 16 + l15) * 264 + quad * 8 + kb);
            acc[mt][0] = __builtin_amdgcn_mfma_f32_16x16x32_bf16(af, bf0, acc[mt][0], 0, 0, 0);
            acc[mt][1] = __builtin_amdgcn_mfma_f32_16x16x32_bf16(af, bf1, acc[mt][1], 0, 0, 0);
        }
    }

#pragma unroll
    for (int mt = 0; mt < 4; ++mt)
#pragma unroll
        for (int nt = 0; nt < 2; ++nt) {
            const int col = nbase + nt * 16 + l15;
            const float bb = ub1[col];
            const float bp = nb2p[col];
#pragma unroll
            for (int r = 0; r < 4; ++r) {
                const int row = mt * 16 + quad * 4 + r;
                float v = acc[mt][nt][r] + bb + s_cnt[row] * bp;
                sH1[row * 136 + col] = f2bf(gelu_f(v));
            }
        }
    __syncthreads();

    f32x4 acc2[4][2];
#pragma unroll
    for (int mt = 0; mt < 4; ++mt)
#pragma unroll
        for (int nt = 0; nt < 2; ++nt) acc2[mt][nt] = (f32x4){0.f, 0.f, 0.f, 0.f};

    const u16* cp0 = W2T + (size_t)(nbase + l15) * 128 + quad * 8;
    const u16* cp1 = cp0 + 16 * 128;
#pragma unroll
    for (int kb = 0; kb < 128; kb += 32) {
        bf16x8 bf0 = *(const bf16x8*)(cp0 + kb);
        bf16x8 bf1 = *(const bf16x8*)(cp1 + kb);
#pragma unroll
        for (int mt = 0; mt < 4; ++mt) {
            bf16x8 af = *(const bf16x8*)(sH1 + (mt * 16 + l15) * 136 + quad * 8 + kb);
            acc2[mt][0] = __builtin_amdgcn_mfma_f32_16x16x32_bf16(af, bf0, acc2[mt][0], 0, 0, 0);
            acc2[mt][1] = __builtin_amdgcn_mfma_f32_16x16x32_bf16(af, bf1, acc2[mt][1], 0, 0, 0);
        }
    }

#pragma unroll
    for (int mt = 0; mt < 4; ++mt)
#pragma unroll
        for (int nt = 0; nt < 2; ++nt) {
            const int col = nbase + nt * 16 + l15;
            const float bb = b2[col];
#pragma unroll
            for (int r = 0; r < 4; ++r) {
                const int row = mt * 16 + quad * 4 + r;
                int n = n0 + row; if (n >= NN) n = NN - 1;
                float h = __uint_as_float((unsigned)hbf[(size_t)n * D + col] << 16);
                sR[row * 132 + col] = acc2[mt][nt][r] + bb + h;
            }
        }
    __syncthreads();

    {
        const int e = tid >> 2, t4 = tid & 3;
        float* rr = sR + e * 132 + t4 * 32;
        float s1 = 0.f, s2 = 0.f;
        float4 v[8];
#pragma unroll
        for (int i = 0; i < 8; ++i) {
            v[i] = *(const float4*)(rr + i * 4);
            s1 += v[i].x + v[i].y + v[i].z + v[i].w;
            s2 += v[i].x * v[i].x + v[i].y * v[i].y + v[i].z * v[i].z + v[i].w * v[i].w;
        }
        s1 += __shfl_xor(s1, 1); s2 += __shfl_xor(s2, 1);
        s1 += __shfl_xor(s1, 2); s2 += __shfl_xor(s2, 2);
        const float mean = s1 * (1.f / 128.f);
        const float var = s2 * (1.f / 128.f) - mean * mean;
        const float rs = rsqrtf(var + LN_EPS);
#pragma unroll
        for (int i = 0; i < 8; ++i) {
            const float4 g = *(const float4*)(gamma + t4 * 32 + i * 4);
            const float4 be = *(const float4*)(beta + t4 * 32 + i * 4);
            float4 o;
            o.x = (v[i].x - mean) * rs * g.x + be.x;
            o.y = (v[i].y - mean) * rs * g.y + be.y;
            o.z = (v[i].z - mean) * rs * g.z + be.z;
            o.w = (v[i].w - mean) * rs * g.w + be.w;
            uint2 pk;
            pk.x = (unsigned)f2bf(o.x) | ((unsigned)f2bf(o.y) << 16);
            pk.y = (unsigned)f2bf(o.z) | ((unsigned)f2bf(o.w) << 16);
            *(uint2*)(sH1 + e * 136 + t4 * 32 + i * 4) = pk;
            if (write_f32) *(float4*)(rr + i * 4) = o;
        }
    }
    __syncthreads();

    {
        const int e = tid >> 2, q = tid & 3;
        const int n = n0 + e;
        if (n < NN) {
            uint4* hp = (uint4*)(hbf_out + (size_t)n * D);
            const u16* sh = sH1 + e * 136;
#pragma unroll
            for (int c = 0; c < 4; ++c) hp[q + c * 4] = *(const uint4*)(sh + (q + c * 4) * 8);
            if (write_f32) {
                float4* op = (float4*)(hidden_out + (size_t)n * D);
                const float* sr = sR + e * 132;
#pragma unroll
                for (int c = 0; c < 8; ++c) op[q + c * 4] = *(const float4*)(sr + (q + c * 4) * 4);
            }
        }
    }

    if (write_f32) {
        const int col = tid & 127, half = tid >> 7;
        const int base = half * 32;
        int cur = s_b[base];
        float acc_p = 0.f;
        for (int i = 0; i < 32; ++i) {
            int b = s_b[base + i];
            if (b < 0) break;
            if (b != cur) { atomicAdd(&pooled[cur * D + col], acc_p); cur = b; acc_p = 0.f; }
            acc_p += sR[(base + i) * 132 + col];
        }
        if (cur >= 0) atomicAdd(&pooled[cur * D + col], acc_p);
    }

    if (PWTnext) {
        const int nbase4 = (tid >> 6) * 64;
        f32x4 accp[4][4];
#pragma unroll
        for (int mt = 0; mt < 4; ++mt)
#pragma unroll
            for (int nt = 0; nt < 4; ++nt) accp[mt][nt] = (f32x4){0.f, 0.f, 0.f, 0.f};

#pragma unroll
        for (int kb = 0; kb < 128; kb += 32) {
            bf16x8 bf[4];
#pragma unroll
            for (int nt = 0; nt < 4; ++nt)
                bf[nt] = *(const bf16x8*)(PWTnext + (size_t)(nbase4 + nt * 16 + l15) * 128 + quad * 8 + kb);
#pragma unroll
            for (int mt = 0; mt < 4; ++mt) {
                bf16x8 af = *(const bf16x8*)(sH1 + (mt * 16 + l15) * 136 + quad * 8 + kb);
#pragma unroll
                for (int nt = 0; nt < 4; ++nt)
                    accp[mt][nt] = __builtin_amdgcn_mfma_f32_16x16x32_bf16(af, bf[nt], accp[mt][nt], 0, 0, 0);
            }
        }
        __syncthreads();
        u16* sP = sA;
#pragma unroll
        for (int mt = 0; mt < 4; ++mt)
#pragma unroll
            for (int nt = 0; nt < 4; ++nt) {
                const int col = nbase4 + nt * 16 + l15;
#pragma unroll
                for (int r = 0; r < 4; ++r)
                    sP[(mt * 16 + quad * 4 + r) * 264 + col] = f2bf(accp[mt][nt][r]);
            }
        __syncthreads();
        const int e = tid >> 2, q = tid & 3;
        const int n = n0 + e;
        if (n < NN) {
            uint4* op = (uint4*)(Pout + (size_t)n * 256);
            const u16* sp = sP + e * 264;
#pragma unroll
            for (int c = 0; c < 8; ++c) op[q + c * 4] = *(const uint4*)(sp + (q + c * 4) * 8);
        }
    }
}

// ---------------- pooling tail ----------------
__global__ __launch_bounds__(256) void count_kernel(
    const int* __restrict__ batch, float* __restrict__ counts)
{
    int t = blockIdx.x * 256 + threadIdx.x;
    const int chunk = (NN + 8191) / 8192;
    int beg = t * chunk, end = beg + chunk;
    if (end > NN) end = NN;
    if (beg >= NN) return;
    int cur = batch[beg];
    float cnt = 0.f;
    for (int i = beg; i < end; ++i) {
        int b = batch[i];
        if (b != cur) { atomicAdd(&counts[cur], cnt); cur = b; cnt = 0.f; }
        cnt += 1.f;
    }
    atomicAdd(&counts[cur], cnt);
}

__global__ __launch_bounds__(256) void pool_div_kernel(
    float* __restrict__ pooled, const float* __restrict__ counts)
{
    int i = blockIdx.x * 256 + threadIdx.x;
    pooled[i] /= fmaxf(counts[i >> 7], 1.0f);
}

extern "C" void kernel_launch(void* const* d_in, const int* in_sizes, int n_in,
                              void* d_out, int out_size, void* d_ws, size_t ws_size,
                              hipStream_t stream) {
    const float* X     = (const float*)d_in[0];
    const int*   eidx  = (const int*)d_in[1];
    const float* ew    = (const float*)d_in[2];
    const int*   batch = (const int*)d_in[3];
    const float* W_in  = (const float*)d_in[5];
    const float* b_in  = (const float*)d_in[6];
    const float* eW1   = (const float*)d_in[7];
    const float* eb1   = (const float*)d_in[8];
    const float* eW2   = (const float*)d_in[9];
    const float* eb2   = (const float*)d_in[10];
    const float* uW1   = (const float*)d_in[11];
    const float* ub1   = (const float*)d_in[12];
    const float* uW2   = (const float*)d_in[13];
    const float* ub2   = (const float*)d_in[14];
    const float* gamma = (const float*)d_in[15];
    const float* beta  = (const float*)d_in[16];

    float* out_hidden = (float*)d_out;
    float* out_pooled = out_hidden + (size_t)NN * D;

    u16*   hbf  = (u16*)d_ws;                                  // N*128 bf16
    u16*   P    = hbf + (size_t)NN * D;                        // N*256 bf16
    u16*   Sbf  = P + (size_t)NN * 256;                        // N*128 bf16
    u16*   PWT  = Sbf + (size_t)NN * D;                        // NL*256*128
    u16*   NW1T = PWT + (size_t)NL * 256 * 128;                // NL*128*256
    u16*   uW2T = NW1T + (size_t)NL * 128 * 256;               // NL*128*128
    float* nb2p = (float*)(uW2T + (size_t)NL * 128 * 128);     // NL*128
    int*   hist    = (int*)(nb2p + (size_t)NL * 128);
    int*   row_ptr = hist + NN;                                // NN+1 ints
    int*   cursor  = row_ptr + NN + 1;
    int*   bsum    = cursor + NN;                              // SCAN_BLOCKS
    int*   boff    = bsum + SCAN_BLOCKS;                       // SCAN_BLOCKS
    int2*  sEdge   = (int2*)(boff + SCAN_BLOCKS + 1);          // NE int2 (8B aligned)
    float* counts  = (float*)(sEdge + NE);

    const int* src = eidx;
    const int* dst = eidx + NE;

    // CSR build (parallel 2-level scan)
    hipMemsetAsync(hist, 0, (size_t)NN * sizeof(int), stream);
    hist_kernel<<<NE / 256, 256, 0, stream>>>(dst, hist);
    bsum_kernel<<<SCAN_BLOCKS, 256, 0, stream>>>(hist, bsum);
    bscan_kernel<<<1, 256, 0, stream>>>(bsum, boff);
    emit_kernel<<<SCAN_BLOCKS, 256, 0, stream>>>(hist, boff, row_ptr, cursor);
    scatter_kernel<<<NE / 256, 256, 0, stream>>>(src, dst, ew, cursor, sEdge);

    // weight prep
    transpose_all_kernel<<<4 * 192, 256, 0, stream>>>(eW1, uW1, uW2, PWT, NW1T, uW2T);
    w2p_kernel<<<192, 256, 0, stream>>>(eW2, uW1, NW1T);
    b2p_kernel<<<NL, 128, 0, stream>>>(eb2, uW1, nb2p);

    input_proj_kernel<<<(NN + 63) / 64, 256, 0, stream>>>(X, W_in, b_in, hbf);

    // pooling buffers ready before the fused last-layer accumulation
    hipMemsetAsync(out_pooled, 0, (size_t)NG * D * sizeof(float), stream);
    hipMemsetAsync(counts, 0, (size_t)NG * sizeof(float), stream);
    count_kernel<<<32, 256, 0, stream>>>(batch, counts);

    const int nblk = (NN + 63) / 64;
    proj_kernel<<<nblk, 256, 0, stream>>>(hbf, PWT, P);   // layer-0 P
    for (int l = 0; l < NL; ++l) {
        edge_csr_kernel<<<(NN * 64 + 255) / 256, 256, 0, stream>>>(
            P, sEdge, row_ptr,
            eW1 + (size_t)l * 257 * 128 + 256 * 128,
            eb1 + (size_t)l * D, Sbf);
        const u16* pwt_next = (l < NL - 1) ? (PWT + (size_t)(l + 1) * 256 * 128) : nullptr;
        node_mfma_kernel<<<nblk, 256, 0, stream>>>(
            hbf, Sbf, hist,
            NW1T + (size_t)l * 128 * 256, ub1 + (size_t)l * D, nb2p + (size_t)l * D,
            uW2T + (size_t)l * 128 * 128, ub2 + (size_t)l * D,
            gamma + (size_t)l * D, beta + (size_t)l * D,
            out_hidden, hbf, pwt_next, P, (l == NL - 1) ? 1 : 0,
            batch, out_pooled);
    }

    pool_div_kernel<<<(NG * D) / 256, 256, 0, stream>>>(out_pooled, counts);
}